// Round 1
// baseline (3382.106 us; speedup 1.0000x reference)
//
#include <hip/hip_runtime.h>
#include <hip/hip_bf16.h>

// Problem constants
#define CC 256      // channels
#define CKD 32      // q/k projection dim
#define NN 4096     // H*W
#define HH 64
#define WW 64
#define BB 4

// ---------------------------------------------------------------------------
// Kernel 1: fused projections for one input x -> q (32xN), k (32xN), vT (NxC)
// grid: (N/64, 20, B), block: 64 (1 wave). blockIdx.y: 0-1 q rows, 2-3 k rows,
// 4-19 v rows (16 o's per block). Weights are wave-uniform -> scalar loads.
// ---------------------------------------------------------------------------
__global__ __launch_bounds__(64) void proj_kernel(
    const float* __restrict__ x,
    const float* __restrict__ wq, const float* __restrict__ bq,
    const float* __restrict__ wk, const float* __restrict__ bk,
    const float* __restrict__ wv, const float* __restrict__ bv,
    float* __restrict__ q, float* __restrict__ k, float* __restrict__ vT) {
  const int lane = threadIdx.x;
  const int n0 = blockIdx.x * 64;
  const int p = blockIdx.y;
  const int b = blockIdx.z;

  const float* w; const float* bias; int o0;
  float* outq = nullptr; float* outv = nullptr;
  if (p < 2)      { w = wq; bias = bq; o0 = p * 16;       outq = q; }
  else if (p < 4) { w = wk; bias = bk; o0 = (p - 2) * 16; outq = k; }
  else            { w = wv; bias = bv; o0 = (p - 4) * 16; outv = vT; }

  const float* xb = x + (size_t)b * CC * NN + n0 + lane;

  float acc[16];
#pragma unroll
  for (int u = 0; u < 16; ++u) acc[u] = bias[o0 + u];

#pragma unroll 4
  for (int c = 0; c < CC; ++c) {
    float xv = xb[(size_t)c * NN];
#pragma unroll
    for (int u = 0; u < 16; ++u) acc[u] += w[(o0 + u) * CC + c] * xv;
  }

  if (outq) {
    float* dst = outq + (size_t)b * CKD * NN + n0 + lane;
#pragma unroll
    for (int u = 0; u < 16; ++u) dst[(size_t)(o0 + u) * NN] = acc[u];
  } else {
    // transpose 64n x 16o tile through LDS, write vT[b][n][c]
    __shared__ float vt_s[64 * 17];
#pragma unroll
    for (int u = 0; u < 16; ++u) vt_s[lane * 17 + u] = acc[u];
    __syncthreads();
    float* dst = outv + (size_t)b * NN * CC + (size_t)n0 * CC + o0;
#pragma unroll
    for (int e = 0; e < 16; ++e) {
      int idx = e * 64 + lane;           // 0..1023
      int nl = idx >> 4, ol = idx & 15;
      dst[nl * CC + ol] = vt_s[nl * 17 + ol];
    }
  }
}

// ---------------------------------------------------------------------------
// Kernel 2: residual branch R = conv1x1(x, wd1, bd1) + conv3x3(x, wd3, bd3)
// grid: (H, 32, B*2), block 64 (one wave = one output row, 8 out channels).
// 3x3 stencil via row registers + __shfl for x+-1, zero-padded edges.
// ---------------------------------------------------------------------------
__global__ __launch_bounds__(64) void conv_kernel(
    const float* __restrict__ x1, const float* __restrict__ x2,
    const float* __restrict__ w1, const float* __restrict__ b1,
    const float* __restrict__ w3, const float* __restrict__ b3,
    float* __restrict__ R1, float* __restrict__ R2) {
  const int lane = threadIdx.x;        // x coordinate
  const int y = blockIdx.x;
  const int o0 = blockIdx.y * 8;
  const int bz = blockIdx.z;
  const int b = bz >> 1, inp = bz & 1;

  const float* X = (inp ? x2 : x1) + (size_t)b * CC * NN;
  float* R = (inp ? R2 : R1) + (size_t)b * CC * NN;

  float acc[8];
#pragma unroll
  for (int u = 0; u < 8; ++u) acc[u] = b1[o0 + u] + b3[o0 + u];

  for (int c = 0; c < CC; ++c) {
    const float* Xc = X + (size_t)c * NN + y * WW + lane;
    float r0 = Xc[0];
    float rm = (y > 0)      ? Xc[-WW] : 0.f;
    float rp = (y < HH - 1) ? Xc[WW]  : 0.f;
    float rml = __shfl_up(rm, 1);   if (lane == 0)  rml = 0.f;
    float r0l = __shfl_up(r0, 1);   if (lane == 0)  r0l = 0.f;
    float rpl = __shfl_up(rp, 1);   if (lane == 0)  rpl = 0.f;
    float rmr = __shfl_down(rm, 1); if (lane == 63) rmr = 0.f;
    float r0r = __shfl_down(r0, 1); if (lane == 63) r0r = 0.f;
    float rpr = __shfl_down(rp, 1); if (lane == 63) rpr = 0.f;
#pragma unroll
    for (int u = 0; u < 8; ++u) {
      int o = o0 + u;
      const float* wc = w3 + ((size_t)o * CC + c) * 9;
      float a = acc[u];
      a += w1[o * CC + c] * r0;
      a += wc[0] * rml + wc[1] * rm + wc[2] * rmr;
      a += wc[3] * r0l + wc[4] * r0 + wc[5] * r0r;
      a += wc[6] * rpl + wc[7] * rp + wc[8] * rpr;
      acc[u] = a;
    }
  }
  float* Rd = R + y * WW + lane;
#pragma unroll
  for (int u = 0; u < 8; ++u) Rd[(size_t)(o0 + u) * NN] = acc[u];
}

// ---------------------------------------------------------------------------
// Kernel 3: flash-style cross attention + fused epilogue
// grid: (N/32, 2, B), block 256 (4 waves). Each block: 32 queries x all 256 c.
// Wave w owns query rows w*8..w*8+7; lane owns channels lane*4..lane*4+3.
// Online softmax over 64-wide j tiles; epilogue out = x + g*(attn/l + R).
// ---------------------------------------------------------------------------
#define SS 68   // padded LDS stride for s tile (16B-aligned, conflict-light)
__global__ __launch_bounds__(256) void attn_kernel(
    const float* __restrict__ q1, const float* __restrict__ k1,
    const float* __restrict__ q2, const float* __restrict__ k2,
    const float* __restrict__ v1T, const float* __restrict__ v2T,
    const float* __restrict__ R1, const float* __restrict__ R2,
    const float* __restrict__ x1, const float* __restrict__ x2,
    const float* __restrict__ g1, const float* __restrict__ g2,
    float* __restrict__ out) {
  const int t = threadIdx.x;
  const int wv = t >> 6, lane = t & 63;
  const int i0 = blockIdx.x * 32;
  const int att = blockIdx.y;
  const int b = blockIdx.z;

  const float *q, *k, *vT, *R, *x;
  float gamma;
  float* o;
  if (att == 0) { q = q1; k = k2; vT = v2T; R = R1; x = x1; gamma = g1[0]; o = out; }
  else          { q = q2; k = k1; vT = v1T; R = R2; x = x2; gamma = g2[0]; o = out + (size_t)BB * CC * NN; }
  q += (size_t)b * CKD * NN;
  k += (size_t)b * CKD * NN;
  vT += (size_t)b * NN * CC;
  R += (size_t)b * CC * NN;
  x += (size_t)b * CC * NN;
  o += (size_t)b * CC * NN;

  __shared__ float q_s[32 * 36];   // [r][d], padded
  __shared__ float s_s[32 * SS];   // [r][j], padded
  __shared__ float mrow[32], lrow[32], arow[32];

  // load q tile: q_s[r][d] = q[d][i0+r]
  for (int idx = t; idx < 32 * 32; idx += 256) {
    int d = idx >> 5, r = idx & 31;
    q_s[r * 36 + d] = q[(size_t)d * NN + i0 + r];
  }
  if (t < 32) { mrow[t] = -1e30f; lrow[t] = 0.f; }

  float acc[8][4];
#pragma unroll
  for (int s = 0; s < 8; ++s)
#pragma unroll
    for (int kk = 0; kk < 4; ++kk) acc[s][kk] = 0.f;
  __syncthreads();

  for (int jt = 0; jt < NN / 64; ++jt) {
    const int j0 = jt * 64;
    // ---- phase 1: S tile (32 q x 64 j), k column in registers
    float kreg[32];
#pragma unroll
    for (int d = 0; d < 32; ++d) kreg[d] = k[(size_t)d * NN + j0 + lane];
#pragma unroll
    for (int s = 0; s < 8; ++s) {
      int r = wv * 8 + s;
      float sv = 0.f;
#pragma unroll
      for (int dc = 0; dc < 8; ++dc) {
        float4 qv = *(const float4*)&q_s[r * 36 + dc * 4];
        sv += qv.x * kreg[dc * 4] + qv.y * kreg[dc * 4 + 1] +
              qv.z * kreg[dc * 4 + 2] + qv.w * kreg[dc * 4 + 3];
      }
      s_s[r * SS + lane] = sv;
    }
    __syncthreads();
    // ---- phase 2: online softmax (8 threads per row)
    {
      int r = t >> 3, sub = t & 7;
      float tm = -1e30f;
#pragma unroll
      for (int kk = 0; kk < 8; ++kk) tm = fmaxf(tm, s_s[r * SS + sub + kk * 8]);
#pragma unroll
      for (int off = 1; off < 8; off <<= 1) tm = fmaxf(tm, __shfl_xor(tm, off));
      float mo = mrow[r];
      float mn = fmaxf(mo, tm);
      float al = __expf(mo - mn);
      float ps = 0.f;
#pragma unroll
      for (int kk = 0; kk < 8; ++kk) {
        int idx = r * SS + sub + kk * 8;
        float pv = __expf(s_s[idx] - mn);
        s_s[idx] = pv;
        ps += pv;
      }
#pragma unroll
      for (int off = 1; off < 8; off <<= 1) ps += __shfl_xor(ps, off);
      if (sub == 0) { lrow[r] = lrow[r] * al + ps; mrow[r] = mn; arow[r] = al; }
    }
    __syncthreads();
    // ---- phase 3: acc += P * V^T  (float4 LDS broadcast x float4 vT loads)
#pragma unroll
    for (int s = 0; s < 8; ++s) {
      float al = arow[wv * 8 + s];
#pragma unroll
      for (int kk = 0; kk < 4; ++kk) acc[s][kk] *= al;
    }
    const float* vbase = vT + (size_t)j0 * CC + lane * 4;
#pragma unroll 2
    for (int jc = 0; jc < 16; ++jc) {
      float4 vv0 = *(const float4*)(vbase + (size_t)(jc * 4 + 0) * CC);
      float4 vv1 = *(const float4*)(vbase + (size_t)(jc * 4 + 1) * CC);
      float4 vv2 = *(const float4*)(vbase + (size_t)(jc * 4 + 2) * CC);
      float4 vv3 = *(const float4*)(vbase + (size_t)(jc * 4 + 3) * CC);
#pragma unroll
      for (int s = 0; s < 8; ++s) {
        float4 pv = *(const float4*)&s_s[(wv * 8 + s) * SS + jc * 4];
        acc[s][0] += pv.x * vv0.x + pv.y * vv1.x + pv.z * vv2.x + pv.w * vv3.x;
        acc[s][1] += pv.x * vv0.y + pv.y * vv1.y + pv.z * vv2.y + pv.w * vv3.y;
        acc[s][2] += pv.x * vv0.z + pv.y * vv1.z + pv.z * vv2.z + pv.w * vv3.z;
        acc[s][3] += pv.x * vv0.w + pv.y * vv1.w + pv.z * vv2.w + pv.w * vv3.w;
      }
    }
    __syncthreads();
  }

  // ---- epilogue: out[c][i] = x + gamma*(acc/l + R)
#pragma unroll
  for (int s = 0; s < 8; ++s) {
    int r = wv * 8 + s;
    float linv = 1.f / lrow[r];
    size_t ibase = (size_t)i0 + r;
#pragma unroll
    for (int kk = 0; kk < 4; ++kk) {
      size_t idx = (size_t)(lane * 4 + kk) * NN + ibase;
      float av = acc[s][kk] * linv;
      o[idx] = x[idx] + gamma * (av + R[idx]);
    }
  }
}

// ---------------------------------------------------------------------------
extern "C" void kernel_launch(void* const* d_in, const int* in_sizes, int n_in,
                              void* d_out, int out_size, void* d_ws, size_t ws_size,
                              hipStream_t stream) {
  const float* x1  = (const float*)d_in[0];
  const float* x2  = (const float*)d_in[1];
  const float* wq1 = (const float*)d_in[2];
  const float* bq1 = (const float*)d_in[3];
  const float* wk1 = (const float*)d_in[4];
  const float* bk1 = (const float*)d_in[5];
  const float* wv1 = (const float*)d_in[6];
  const float* bv1 = (const float*)d_in[7];
  const float* wq2 = (const float*)d_in[8];
  const float* bq2 = (const float*)d_in[9];
  const float* wk2 = (const float*)d_in[10];
  const float* bk2 = (const float*)d_in[11];
  const float* wv2 = (const float*)d_in[12];
  const float* bv2 = (const float*)d_in[13];
  const float* wd1 = (const float*)d_in[14];
  const float* bd1 = (const float*)d_in[15];
  const float* wd3 = (const float*)d_in[16];
  const float* bd3 = (const float*)d_in[17];
  const float* g1  = (const float*)d_in[18];
  const float* g2  = (const float*)d_in[19];
  float* out = (float*)d_out;
  float* ws  = (float*)d_ws;

  // workspace layout (floats)
  const size_t QSZ = (size_t)BB * CKD * NN;   // 524288
  const size_t VSZ = (size_t)BB * NN * CC;    // 4194304
  float* q1  = ws;
  float* k1  = q1 + QSZ;
  float* q2  = k1 + QSZ;
  float* k2  = q2 + QSZ;
  float* v1T = k2 + QSZ;
  float* v2T = v1T + VSZ;
  float* R1  = v2T + VSZ;
  float* R2  = R1 + VSZ;

  dim3 pgrid(NN / 64, 20, BB);
  proj_kernel<<<pgrid, 64, 0, stream>>>(x1, wq1, bq1, wk1, bk1, wv1, bv1, q1, k1, v1T);
  proj_kernel<<<pgrid, 64, 0, stream>>>(x2, wq2, bq2, wk2, bk2, wv2, bv2, q2, k2, v2T);

  dim3 cgrid(HH, CC / 8, BB * 2);
  conv_kernel<<<cgrid, 64, 0, stream>>>(x1, x2, wd1, bd1, wd3, bd3, R1, R2);

  dim3 agrid(NN / 32, 2, BB);
  attn_kernel<<<agrid, 256, 0, stream>>>(q1, k1, q2, k2, v1T, v2T, R1, R2,
                                         x1, x2, g1, g2, out);
}

// Round 2
// 1701.137 us; speedup vs baseline: 1.9881x; 1.9881x over previous
//
#include <hip/hip_runtime.h>
#include <hip/hip_bf16.h>

// Problem constants
#define CC 256      // channels
#define CKD 32      // q/k projection dim
#define NN 4096     // H*W
#define HH 64
#define WW 64
#define BB 4

typedef __attribute__((ext_vector_type(8))) short short8;   // 8 bf16 (4 VGPRs)
typedef __attribute__((ext_vector_type(4))) float floatx4;  // MFMA C/D frag

__device__ __forceinline__ unsigned short f2bf(float f) {
  union { float f; unsigned u; } v; v.f = f;
  unsigned r = v.u + 0x7fffu + ((v.u >> 16) & 1u);   // RNE
  return (unsigned short)(r >> 16);
}

// ---------------------------------------------------------------------------
// Kernel 1: fused projections for one input x.
// Outputs (bf16, MFMA-frag-friendly):
//   Qpack[b][n][32], Kpack[b][n][32]  (row-major, d contiguous)
//   Vpack[b][n>>3][c][n&7]            (8-j groups contiguous per c)
// grid: (N/64, 20, B), block 64 (1 wave). y: 0-1 q, 2-3 k, 4-19 v (16 o each).
// ---------------------------------------------------------------------------
__global__ __launch_bounds__(64) void proj_kernel(
    const float* __restrict__ x,
    const float* __restrict__ wq, const float* __restrict__ bq,
    const float* __restrict__ wk, const float* __restrict__ bk,
    const float* __restrict__ wv, const float* __restrict__ bv,
    unsigned short* __restrict__ Qp, unsigned short* __restrict__ Kp,
    unsigned short* __restrict__ Vp) {
  const int lane = threadIdx.x;
  const int n0 = blockIdx.x * 64;
  const int p = blockIdx.y;
  const int b = blockIdx.z;

  const float* w; const float* bias; int o0; int kind;
  if (p < 2)      { w = wq; bias = bq; o0 = p * 16;       kind = 0; }
  else if (p < 4) { w = wk; bias = bk; o0 = (p - 2) * 16; kind = 1; }
  else            { w = wv; bias = bv; o0 = (p - 4) * 16; kind = 2; }

  const float* xb = x + (size_t)b * CC * NN + n0 + lane;

  float acc[16];
#pragma unroll
  for (int u = 0; u < 16; ++u) acc[u] = bias[o0 + u];

#pragma unroll 4
  for (int c = 0; c < CC; ++c) {
    float xv = xb[(size_t)c * NN];
#pragma unroll
    for (int u = 0; u < 16; ++u) acc[u] += w[(o0 + u) * CC + c] * xv;
  }

  if (kind < 2) {
    // lane owns (n0+lane, o0..o0+15): contiguous in d -> two 16B stores
    unsigned short* dst = (kind == 0 ? Qp : Kp) + (size_t)b * NN * CKD +
                          (size_t)(n0 + lane) * CKD + o0;
#pragma unroll
    for (int h = 0; h < 2; ++h) {
      short8 v;
#pragma unroll
      for (int u = 0; u < 8; ++u) v[u] = (short)f2bf(acc[h * 8 + u]);
      *(short8*)(dst + h * 8) = v;
    }
  } else {
    // transpose 64n x 16o through LDS, emit Vpack 16B rows
    __shared__ float vt_s[64 * 17];
#pragma unroll
    for (int u = 0; u < 16; ++u) vt_s[lane * 17 + u] = acc[u];
    __syncthreads();
    unsigned short* dst0 = Vp + (size_t)b * NN * CC;
#pragma unroll
    for (int e = 0; e < 2; ++e) {
      int id = e * 64 + lane;          // 0..127
      int gl = id >> 4, oo = id & 15;  // j-group (of 8), o within chunk
      short8 v;
#pragma unroll
      for (int jj = 0; jj < 8; ++jj)
        v[jj] = (short)f2bf(vt_s[(gl * 8 + jj) * 17 + oo]);
      *(short8*)(dst0 + ((size_t)((n0 >> 3) + gl) * CC + (o0 + oo)) * 8) = v;
    }
  }
}

// ---------------------------------------------------------------------------
// Kernel 2: residual branch R = conv1x1 + conv3x3 (fp32, unchanged)
// ---------------------------------------------------------------------------
__global__ __launch_bounds__(64) void conv_kernel(
    const float* __restrict__ x1, const float* __restrict__ x2,
    const float* __restrict__ w1, const float* __restrict__ b1,
    const float* __restrict__ w3, const float* __restrict__ b3,
    float* __restrict__ R1, float* __restrict__ R2) {
  const int lane = threadIdx.x;
  const int y = blockIdx.x;
  const int o0 = blockIdx.y * 8;
  const int bz = blockIdx.z;
  const int b = bz >> 1, inp = bz & 1;

  const float* X = (inp ? x2 : x1) + (size_t)b * CC * NN;
  float* R = (inp ? R2 : R1) + (size_t)b * CC * NN;

  float acc[8];
#pragma unroll
  for (int u = 0; u < 8; ++u) acc[u] = b1[o0 + u] + b3[o0 + u];

  for (int c = 0; c < CC; ++c) {
    const float* Xc = X + (size_t)c * NN + y * WW + lane;
    float r0 = Xc[0];
    float rm = (y > 0)      ? Xc[-WW] : 0.f;
    float rp = (y < HH - 1) ? Xc[WW]  : 0.f;
    float rml = __shfl_up(rm, 1);   if (lane == 0)  rml = 0.f;
    float r0l = __shfl_up(r0, 1);   if (lane == 0)  r0l = 0.f;
    float rpl = __shfl_up(rp, 1);   if (lane == 0)  rpl = 0.f;
    float rmr = __shfl_down(rm, 1); if (lane == 63) rmr = 0.f;
    float r0r = __shfl_down(r0, 1); if (lane == 63) r0r = 0.f;
    float rpr = __shfl_down(rp, 1); if (lane == 63) rpr = 0.f;
#pragma unroll
    for (int u = 0; u < 8; ++u) {
      int o = o0 + u;
      const float* wc = w3 + ((size_t)o * CC + c) * 9;
      float a = acc[u];
      a += w1[o * CC + c] * r0;
      a += wc[0] * rml + wc[1] * rm + wc[2] * rmr;
      a += wc[3] * r0l + wc[4] * r0 + wc[5] * r0r;
      a += wc[6] * rpl + wc[7] * rp + wc[8] * rpr;
      acc[u] = a;
    }
  }
  float* Rd = R + y * WW + lane;
#pragma unroll
  for (int u = 0; u < 8; ++u) Rd[(size_t)(o0 + u) * NN] = acc[u];
}

// ---------------------------------------------------------------------------
// Kernel 3: MFMA flash attention + fused epilogue
// grid (N/64, 2, B), block 256 = 4 waves. 64 queries/block.
// Pass 1: row max via QK^T MFMAs (K=32 in one 16x16x32 inst).
// Pass 2: S -> exp -> P (bf16, LDS dbuf) -> P*V^T MFMAs, l accumulated.
// Wave w: softmax rows w*16..w*16+15; GEMM2 c-slice w*64..w*64+63 (all 64 i).
// Epilogue: out = x + gamma*(acc/l + R), 16B stores (4 consecutive i / reg).
// ---------------------------------------------------------------------------
__global__ __launch_bounds__(256) void attn_kernel(
    const unsigned short* __restrict__ Qp1, const unsigned short* __restrict__ Kp1,
    const unsigned short* __restrict__ Qp2, const unsigned short* __restrict__ Kp2,
    const unsigned short* __restrict__ Vp1, const unsigned short* __restrict__ Vp2,
    const float* __restrict__ R1, const float* __restrict__ R2,
    const float* __restrict__ x1, const float* __restrict__ x2,
    const float* __restrict__ g1, const float* __restrict__ g2,
    float* __restrict__ out) {
  const int t = threadIdx.x;
  const int w = t >> 6, lane = t & 63;
  const int l15 = lane & 15, g = lane >> 4;
  const int i0 = blockIdx.x * 64;
  const int att = blockIdx.y, b = blockIdx.z;

  const unsigned short *Qp, *Kp, *Vp; const float *R, *x; float gamma; float* o;
  if (att == 0) { Qp = Qp1; Kp = Kp2; Vp = Vp2; R = R1; x = x1; gamma = g1[0]; o = out; }
  else          { Qp = Qp2; Kp = Kp1; Vp = Vp1; R = R2; x = x2; gamma = g2[0];
                  o = out + (size_t)BB * CC * NN; }
  Qp += (size_t)b * NN * CKD; Kp += (size_t)b * NN * CKD; Vp += (size_t)b * NN * CC;
  R += (size_t)b * CC * NN; x += (size_t)b * CC * NN; o += (size_t)b * CC * NN;

  __shared__ unsigned short p_s[2][64][72];  // stride 72 -> 2-way banks (free)
  __shared__ float l_s[64];

  // Q A-frag (held entire kernel): row i0+w*16+l15, d = g*8..g*8+7
  short8 aq = *(const short8*)(Qp + (size_t)(i0 + w * 16 + l15) * CKD + g * 8);

  // ---- pass 1: global row max
  float m[4] = {-1e30f, -1e30f, -1e30f, -1e30f};
  for (int jt = 0; jt < NN / 64; ++jt) {
    const unsigned short* kb = Kp + (size_t)jt * 64 * CKD + l15 * CKD + g * 8;
#pragma unroll
    for (int js = 0; js < 4; ++js) {
      short8 bk = *(const short8*)(kb + js * 16 * CKD);
      floatx4 z = {0.f, 0.f, 0.f, 0.f};
      floatx4 s = __builtin_amdgcn_mfma_f32_16x16x32_bf16(aq, bk, z, 0, 0, 0);
#pragma unroll
      for (int r = 0; r < 4; ++r) m[r] = fmaxf(m[r], s[r]);
    }
  }
#pragma unroll
  for (int off = 1; off < 16; off <<= 1) {
#pragma unroll
    for (int r = 0; r < 4; ++r) m[r] = fmaxf(m[r], __shfl_xor(m[r], off));
  }

  // ---- pass 2: exp + P*V^T
  float l[4] = {0.f, 0.f, 0.f, 0.f};
  floatx4 acc[4][4];
#pragma unroll
  for (int a = 0; a < 4; ++a)
#pragma unroll
    for (int c = 0; c < 4; ++c) acc[a][c] = (floatx4){0.f, 0.f, 0.f, 0.f};

  for (int jt = 0; jt < NN / 64; ++jt) {
    const int buf = jt & 1;
    const unsigned short* kb = Kp + (size_t)jt * 64 * CKD + l15 * CKD + g * 8;
#pragma unroll
    for (int js = 0; js < 4; ++js) {
      short8 bk = *(const short8*)(kb + js * 16 * CKD);
      floatx4 z = {0.f, 0.f, 0.f, 0.f};
      floatx4 s = __builtin_amdgcn_mfma_f32_16x16x32_bf16(aq, bk, z, 0, 0, 0);
#pragma unroll
      for (int r = 0; r < 4; ++r) {
        float pv = __expf(s[r] - m[r]);
        l[r] += pv;
        p_s[buf][w * 16 + g * 4 + r][js * 16 + l15] = f2bf(pv);
      }
    }
    __syncthreads();
#pragma unroll
    for (int ks = 0; ks < 2; ++ks) {
      short8 ap[4];
#pragma unroll
      for (int isub = 0; isub < 4; ++isub)
        ap[isub] = *(const short8*)&p_s[buf][isub * 16 + l15][ks * 32 + g * 8];
#pragma unroll
      for (int cs = 0; cs < 4; ++cs) {
        short8 bv = *(const short8*)(Vp +
            ((size_t)(jt * 8 + ks * 4 + g) * CC + (w * 64 + cs * 16 + l15)) * 8);
#pragma unroll
        for (int isub = 0; isub < 4; ++isub)
          acc[isub][cs] =
              __builtin_amdgcn_mfma_f32_16x16x32_bf16(ap[isub], bv, acc[isub][cs], 0, 0, 0);
      }
    }
  }

  // ---- finalize l and share across waves
#pragma unroll
  for (int off = 1; off < 16; off <<= 1) {
#pragma unroll
    for (int r = 0; r < 4; ++r) l[r] += __shfl_xor(l[r], off);
  }
  if (l15 == 0) {
#pragma unroll
    for (int r = 0; r < 4; ++r) l_s[w * 16 + g * 4 + r] = l[r];
  }
  __syncthreads();

  // ---- epilogue: out[c][i] = x + gamma*(acc/l + R)
#pragma unroll
  for (int isub = 0; isub < 4; ++isub) {
    float linv[4];
#pragma unroll
    for (int r = 0; r < 4; ++r) linv[r] = 1.f / l_s[isub * 16 + g * 4 + r];
#pragma unroll
    for (int cs = 0; cs < 4; ++cs) {
      int c = w * 64 + cs * 16 + l15;
      size_t base = (size_t)c * NN + i0 + isub * 16 + g * 4;
      float4 xr = *(const float4*)(x + base);
      float4 rr = *(const float4*)(R + base);
      float4 ov;
      ov.x = xr.x + gamma * (acc[isub][cs][0] * linv[0] + rr.x);
      ov.y = xr.y + gamma * (acc[isub][cs][1] * linv[1] + rr.y);
      ov.z = xr.z + gamma * (acc[isub][cs][2] * linv[2] + rr.z);
      ov.w = xr.w + gamma * (acc[isub][cs][3] * linv[3] + rr.w);
      *(float4*)(o + base) = ov;
    }
  }
}

// ---------------------------------------------------------------------------
extern "C" void kernel_launch(void* const* d_in, const int* in_sizes, int n_in,
                              void* d_out, int out_size, void* d_ws, size_t ws_size,
                              hipStream_t stream) {
  const float* x1  = (const float*)d_in[0];
  const float* x2  = (const float*)d_in[1];
  const float* wq1 = (const float*)d_in[2];
  const float* bq1 = (const float*)d_in[3];
  const float* wk1 = (const float*)d_in[4];
  const float* bk1 = (const float*)d_in[5];
  const float* wv1 = (const float*)d_in[6];
  const float* bv1 = (const float*)d_in[7];
  const float* wq2 = (const float*)d_in[8];
  const float* bq2 = (const float*)d_in[9];
  const float* wk2 = (const float*)d_in[10];
  const float* bk2 = (const float*)d_in[11];
  const float* wv2 = (const float*)d_in[12];
  const float* bv2 = (const float*)d_in[13];
  const float* wd1 = (const float*)d_in[14];
  const float* bd1 = (const float*)d_in[15];
  const float* wd3 = (const float*)d_in[16];
  const float* bd3 = (const float*)d_in[17];
  const float* g1  = (const float*)d_in[18];
  const float* g2  = (const float*)d_in[19];
  float* out = (float*)d_out;

  // workspace layout (bytes)
  const size_t QB = (size_t)BB * NN * CKD * 2;   // 1 MB
  const size_t VB = (size_t)BB * NN * CC * 2;    // 8 MB
  const size_t RB = (size_t)BB * NN * CC * 4;    // 16 MB
  char* base = (char*)d_ws;
  unsigned short* Qp1 = (unsigned short*)(base);
  unsigned short* Kp1 = (unsigned short*)(base + QB);
  unsigned short* Qp2 = (unsigned short*)(base + 2 * QB);
  unsigned short* Kp2 = (unsigned short*)(base + 3 * QB);
  unsigned short* Vp1 = (unsigned short*)(base + 4 * QB);
  unsigned short* Vp2 = (unsigned short*)(base + 4 * QB + VB);
  float* R1 = (float*)(base + 4 * QB + 2 * VB);
  float* R2 = (float*)(base + 4 * QB + 2 * VB + RB);

  dim3 pgrid(NN / 64, 20, BB);
  proj_kernel<<<pgrid, 64, 0, stream>>>(x1, wq1, bq1, wk1, bk1, wv1, bv1, Qp1, Kp1, Vp1);
  proj_kernel<<<pgrid, 64, 0, stream>>>(x2, wq2, bq2, wk2, bk2, wv2, bv2, Qp2, Kp2, Vp2);

  dim3 cgrid(HH, CC / 8, BB * 2);
  conv_kernel<<<cgrid, 64, 0, stream>>>(x1, x2, wd1, bd1, wd3, bd3, R1, R2);

  dim3 agrid(NN / 64, 2, BB);
  attn_kernel<<<agrid, 256, 0, stream>>>(Qp1, Kp1, Qp2, Kp2, Vp1, Vp2,
                                         R1, R2, x1, x2, g1, g2, out);
}

// Round 3
// 562.922 us; speedup vs baseline: 6.0081x; 3.0220x over previous
//
#include <hip/hip_runtime.h>
#include <hip/hip_bf16.h>

// Problem constants
#define CC 256      // channels
#define CKD 32      // q/k projection dim
#define NN 4096     // H*W
#define HH 64
#define WW 64
#define BB 4

typedef __attribute__((ext_vector_type(8))) short short8;   // 8 bf16 (4 VGPRs)
typedef __attribute__((ext_vector_type(4))) float floatx4;  // MFMA C/D frag

__device__ __forceinline__ unsigned short f2bf(float f) {
  union { float f; unsigned u; } v; v.f = f;
  unsigned r = v.u + 0x7fffu + ((v.u >> 16) & 1u);   // RNE
  return (unsigned short)(r >> 16);
}

// ---------------------------------------------------------------------------
// Kernel 0a: pack x (fp32 [img][c][n]) -> Xp (bf16 [img][n][c], c contiguous)
// grid (64, 4, 8), block 256. 64n x 64c tile through LDS.
// ---------------------------------------------------------------------------
__global__ __launch_bounds__(256) void xpack_kernel(
    const float* __restrict__ x1, const float* __restrict__ x2,
    unsigned short* __restrict__ Xp) {
  const int t = threadIdx.x;
  const int nb = blockIdx.x, cbk = blockIdx.y, img = blockIdx.z;
  const float* X = ((img >> 2) ? x2 : x1) + (size_t)(img & 3) * CC * NN;
  const int n0 = nb * 64, c0 = cbk * 64;
  __shared__ float tile[64][65];
  const int nl = t & 63, cl0 = t >> 6;
#pragma unroll
  for (int i = 0; i < 16; ++i)
    tile[cl0 + i * 4][nl] = X[(size_t)(c0 + cl0 + i * 4) * NN + n0 + nl];
  __syncthreads();
#pragma unroll
  for (int it = 0; it < 2; ++it) {
    int id = it * 256 + t;
    int nl2 = id >> 3, cc = id & 7;
    short8 v;
#pragma unroll
    for (int j = 0; j < 8; ++j) v[j] = (short)f2bf(tile[cc * 8 + j][nl2]);
    *(short8*)(Xp + (size_t)img * NN * CC + (size_t)(n0 + nl2) * CC + c0 + cc * 8) = v;
  }
}

// ---------------------------------------------------------------------------
// Kernel 0b: pack weights -> Wp (bf16 [tap][o][c]); tap 0..8 = 3x3, tap 9 = 1x1
// grid 256, block 256: one thread per (o,c).
// ---------------------------------------------------------------------------
__global__ __launch_bounds__(256) void wpack_kernel(
    const float* __restrict__ wd1, const float* __restrict__ wd3,
    unsigned short* __restrict__ Wp) {
  const int id = blockIdx.x * 256 + threadIdx.x;  // o*256 + c
#pragma unroll
  for (int tap = 0; tap < 10; ++tap) {
    float v = (tap < 9) ? wd3[(size_t)id * 9 + tap] : wd1[id];
    Wp[(size_t)tap * (CC * CC) + id] = f2bf(v);
  }
}

// ---------------------------------------------------------------------------
// Kernel 1: fused projections for one input x.
//   Qpack[b][n][32], Kpack[b][n][32]  (row-major, d contiguous)
//   Vpack[b][n>>3][c][n&7]            (8-j groups contiguous per c)
// grid: (N/64, 20, B), block 64.
// ---------------------------------------------------------------------------
__global__ __launch_bounds__(64) void proj_kernel(
    const float* __restrict__ x,
    const float* __restrict__ wq, const float* __restrict__ bq,
    const float* __restrict__ wk, const float* __restrict__ bk,
    const float* __restrict__ wv, const float* __restrict__ bv,
    unsigned short* __restrict__ Qp, unsigned short* __restrict__ Kp,
    unsigned short* __restrict__ Vp) {
  const int lane = threadIdx.x;
  const int n0 = blockIdx.x * 64;
  const int p = blockIdx.y;
  const int b = blockIdx.z;

  const float* w; const float* bias; int o0; int kind;
  if (p < 2)      { w = wq; bias = bq; o0 = p * 16;       kind = 0; }
  else if (p < 4) { w = wk; bias = bk; o0 = (p - 2) * 16; kind = 1; }
  else            { w = wv; bias = bv; o0 = (p - 4) * 16; kind = 2; }

  const float* xb = x + (size_t)b * CC * NN + n0 + lane;

  float acc[16];
#pragma unroll
  for (int u = 0; u < 16; ++u) acc[u] = bias[o0 + u];

#pragma unroll 4
  for (int c = 0; c < CC; ++c) {
    float xv = xb[(size_t)c * NN];
#pragma unroll
    for (int u = 0; u < 16; ++u) acc[u] += w[(o0 + u) * CC + c] * xv;
  }

  if (kind < 2) {
    unsigned short* dst = (kind == 0 ? Qp : Kp) + (size_t)b * NN * CKD +
                          (size_t)(n0 + lane) * CKD + o0;
#pragma unroll
    for (int h = 0; h < 2; ++h) {
      short8 v;
#pragma unroll
      for (int u = 0; u < 8; ++u) v[u] = (short)f2bf(acc[h * 8 + u]);
      *(short8*)(dst + h * 8) = v;
    }
  } else {
    __shared__ float vt_s[64 * 17];
#pragma unroll
    for (int u = 0; u < 16; ++u) vt_s[lane * 17 + u] = acc[u];
    __syncthreads();
    unsigned short* dst0 = Vp + (size_t)b * NN * CC;
#pragma unroll
    for (int e = 0; e < 2; ++e) {
      int id = e * 64 + lane;
      int gl = id >> 4, oo = id & 15;
      short8 v;
#pragma unroll
      for (int jj = 0; jj < 8; ++jj)
        v[jj] = (short)f2bf(vt_s[(gl * 8 + jj) * 17 + oo]);
      *(short8*)(dst0 + ((size_t)((n0 >> 3) + gl) * CC + (o0 + oo)) * 8) = v;
    }
  }
}

// ---------------------------------------------------------------------------
// Kernel 2: implicit-GEMM MFMA conv: R = conv1x1 + conv3x3 (+biases)
// GEMM: M=256 o, N=pixels, K = c x 10 taps. Block: 128 o x 128 pix (2 rows),
// 4 waves of 64x64 (16 MFMAs / K32-step). LDS: pixel tile with halo
// xs[4 rows][66 cols][72 c-pad], weight slice ws[128][72]. Tap = LDS shift.
// grid (32, 2, 8), block 256.
// ---------------------------------------------------------------------------
__global__ __launch_bounds__(256) void conv_mfma_kernel(
    const unsigned short* __restrict__ Xp, const unsigned short* __restrict__ Wp,
    const float* __restrict__ bd1, const float* __restrict__ bd3,
    float* __restrict__ R1, float* __restrict__ R2) {
  const int t = threadIdx.x;
  const int w = t >> 6, lane = t & 63;
  const int l15 = lane & 15, g = lane >> 4;
  const int pb = blockIdx.x, ob = blockIdx.y, img = blockIdx.z;
  const int o0 = ob * 128, n0 = pb * 128, y0 = pb * 2;
  const int wm = w >> 1, wn = w & 1;

  const unsigned short* Xi = Xp + (size_t)img * NN * CC;
  float* R = ((img >> 2) ? R2 : R1) + (size_t)(img & 3) * CC * NN;

  __shared__ unsigned short xs[4][66][72];  // rows y0-1..y0+2, cols -1..64
  __shared__ unsigned short ws[128][72];

  floatx4 acc[4][4];
#pragma unroll
  for (int m = 0; m < 4; ++m)
#pragma unroll
    for (int n = 0; n < 4; ++n) acc[m][n] = (floatx4){0.f, 0.f, 0.f, 0.f};

  for (int cb = 0; cb < 4; ++cb) {
    const int c0 = cb * 64;
    __syncthreads();   // previous iter's xs reads complete
    // stage pixel tile (4 rows x 66 cols x 64 c), zero halo at image edges
#pragma unroll
    for (int it = 0; it < 9; ++it) {
      int id = it * 256 + t;
      if (id < 2112) {                 // 4*66*8 16B-chunks
        int r = id / 528, rem = id % 528;
        int col = rem >> 3, cc = rem & 7;
        int y = y0 - 1 + r, x = col - 1;
        short8 v = {0, 0, 0, 0, 0, 0, 0, 0};
        if (y >= 0 && y < HH && x >= 0 && x < WW)
          v = *(const short8*)(Xi + (size_t)(y * WW + x) * CC + c0 + cc * 8);
        *(short8*)&xs[r][col][cc * 8] = v;
      }
    }
    for (int tap = 0; tap < 10; ++tap) {
      __syncthreads();   // xs ready (tap 0) / previous ws reads complete
#pragma unroll
      for (int it = 0; it < 4; ++it) {
        int id = it * 256 + t;
        int ol = id >> 3, cc = id & 7;
        *(short8*)&ws[ol][cc * 8] = *(const short8*)(
            Wp + (size_t)(tap * CC + o0 + ol) * CC + c0 + cc * 8);
      }
      __syncthreads();   // ws ready
      const int dy = (tap < 9) ? tap / 3 - 1 : 0;
      const int dx = (tap < 9) ? tap % 3 - 1 : 0;
      const int rrow = 1 + wn + dy;
#pragma unroll
      for (int ks = 0; ks < 2; ++ks) {
        short8 af[4], bf[4];
#pragma unroll
        for (int m = 0; m < 4; ++m)
          af[m] = *(const short8*)&ws[wm * 64 + m * 16 + l15][ks * 32 + g * 8];
#pragma unroll
        for (int n = 0; n < 4; ++n)
          bf[n] = *(const short8*)&xs[rrow][1 + n * 16 + l15 + dx][ks * 32 + g * 8];
#pragma unroll
        for (int m = 0; m < 4; ++m)
#pragma unroll
          for (int n = 0; n < 4; ++n)
            acc[m][n] = __builtin_amdgcn_mfma_f32_16x16x32_bf16(
                af[m], bf[n], acc[m][n], 0, 0, 0);
      }
    }
  }

  // epilogue: R[o][pix] = acc + bd1[o] + bd3[o]
#pragma unroll
  for (int m = 0; m < 4; ++m) {
    int ob2 = o0 + wm * 64 + m * 16 + g * 4;
    float bs[4];
#pragma unroll
    for (int r = 0; r < 4; ++r) bs[r] = bd1[ob2 + r] + bd3[ob2 + r];
#pragma unroll
    for (int n = 0; n < 4; ++n) {
      int pix = n0 + wn * 64 + n * 16 + l15;
#pragma unroll
      for (int r = 0; r < 4; ++r)
        R[(size_t)(ob2 + r) * NN + pix] = acc[m][n][r] + bs[r];
    }
  }
}

// ---------------------------------------------------------------------------
// Kernel 3: MFMA flash attention + fused epilogue (unchanged from R2)
// ---------------------------------------------------------------------------
__global__ __launch_bounds__(256) void attn_kernel(
    const unsigned short* __restrict__ Qp1, const unsigned short* __restrict__ Kp1,
    const unsigned short* __restrict__ Qp2, const unsigned short* __restrict__ Kp2,
    const unsigned short* __restrict__ Vp1, const unsigned short* __restrict__ Vp2,
    const float* __restrict__ R1, const float* __restrict__ R2,
    const float* __restrict__ x1, const float* __restrict__ x2,
    const float* __restrict__ g1, const float* __restrict__ g2,
    float* __restrict__ out) {
  const int t = threadIdx.x;
  const int w = t >> 6, lane = t & 63;
  const int l15 = lane & 15, g = lane >> 4;
  const int i0 = blockIdx.x * 64;
  const int att = blockIdx.y, b = blockIdx.z;

  const unsigned short *Qp, *Kp, *Vp; const float *R, *x; float gamma; float* o;
  if (att == 0) { Qp = Qp1; Kp = Kp2; Vp = Vp2; R = R1; x = x1; gamma = g1[0]; o = out; }
  else          { Qp = Qp2; Kp = Kp1; Vp = Vp1; R = R2; x = x2; gamma = g2[0];
                  o = out + (size_t)BB * CC * NN; }
  Qp += (size_t)b * NN * CKD; Kp += (size_t)b * NN * CKD; Vp += (size_t)b * NN * CC;
  R += (size_t)b * CC * NN; x += (size_t)b * CC * NN; o += (size_t)b * CC * NN;

  __shared__ unsigned short p_s[2][64][72];
  __shared__ float l_s[64];

  short8 aq = *(const short8*)(Qp + (size_t)(i0 + w * 16 + l15) * CKD + g * 8);

  // pass 1: global row max
  float m[4] = {-1e30f, -1e30f, -1e30f, -1e30f};
  for (int jt = 0; jt < NN / 64; ++jt) {
    const unsigned short* kb = Kp + (size_t)jt * 64 * CKD + l15 * CKD + g * 8;
#pragma unroll
    for (int js = 0; js < 4; ++js) {
      short8 bk = *(const short8*)(kb + js * 16 * CKD);
      floatx4 z = {0.f, 0.f, 0.f, 0.f};
      floatx4 s = __builtin_amdgcn_mfma_f32_16x16x32_bf16(aq, bk, z, 0, 0, 0);
#pragma unroll
      for (int r = 0; r < 4; ++r) m[r] = fmaxf(m[r], s[r]);
    }
  }
#pragma unroll
  for (int off = 1; off < 16; off <<= 1) {
#pragma unroll
    for (int r = 0; r < 4; ++r) m[r] = fmaxf(m[r], __shfl_xor(m[r], off));
  }

  // pass 2: exp + P*V^T
  float l[4] = {0.f, 0.f, 0.f, 0.f};
  floatx4 acc[4][4];
#pragma unroll
  for (int a = 0; a < 4; ++a)
#pragma unroll
    for (int c = 0; c < 4; ++c) acc[a][c] = (floatx4){0.f, 0.f, 0.f, 0.f};

  for (int jt = 0; jt < NN / 64; ++jt) {
    const int buf = jt & 1;
    const unsigned short* kb = Kp + (size_t)jt * 64 * CKD + l15 * CKD + g * 8;
#pragma unroll
    for (int js = 0; js < 4; ++js) {
      short8 bk = *(const short8*)(kb + js * 16 * CKD);
      floatx4 z = {0.f, 0.f, 0.f, 0.f};
      floatx4 s = __builtin_amdgcn_mfma_f32_16x16x32_bf16(aq, bk, z, 0, 0, 0);
#pragma unroll
      for (int r = 0; r < 4; ++r) {
        float pv = __expf(s[r] - m[r]);
        l[r] += pv;
        p_s[buf][w * 16 + g * 4 + r][js * 16 + l15] = f2bf(pv);
      }
    }
    __syncthreads();
#pragma unroll
    for (int ks = 0; ks < 2; ++ks) {
      short8 ap[4];
#pragma unroll
      for (int isub = 0; isub < 4; ++isub)
        ap[isub] = *(const short8*)&p_s[buf][isub * 16 + l15][ks * 32 + g * 8];
#pragma unroll
      for (int cs = 0; cs < 4; ++cs) {
        short8 bv = *(const short8*)(Vp +
            ((size_t)(jt * 8 + ks * 4 + g) * CC + (w * 64 + cs * 16 + l15)) * 8);
#pragma unroll
        for (int isub = 0; isub < 4; ++isub)
          acc[isub][cs] =
              __builtin_amdgcn_mfma_f32_16x16x32_bf16(ap[isub], bv, acc[isub][cs], 0, 0, 0);
      }
    }
  }

#pragma unroll
  for (int off = 1; off < 16; off <<= 1) {
#pragma unroll
    for (int r = 0; r < 4; ++r) l[r] += __shfl_xor(l[r], off);
  }
  if (l15 == 0) {
#pragma unroll
    for (int r = 0; r < 4; ++r) l_s[w * 16 + g * 4 + r] = l[r];
  }
  __syncthreads();

#pragma unroll
  for (int isub = 0; isub < 4; ++isub) {
    float linv[4];
#pragma unroll
    for (int r = 0; r < 4; ++r) linv[r] = 1.f / l_s[isub * 16 + g * 4 + r];
#pragma unroll
    for (int cs = 0; cs < 4; ++cs) {
      int c = w * 64 + cs * 16 + l15;
      size_t base = (size_t)c * NN + i0 + isub * 16 + g * 4;
      float4 xr = *(const float4*)(x + base);
      float4 rr = *(const float4*)(R + base);
      float4 ov;
      ov.x = xr.x + gamma * (acc[isub][cs][0] * linv[0] + rr.x);
      ov.y = xr.y + gamma * (acc[isub][cs][1] * linv[1] + rr.y);
      ov.z = xr.z + gamma * (acc[isub][cs][2] * linv[2] + rr.z);
      ov.w = xr.w + gamma * (acc[isub][cs][3] * linv[3] + rr.w);
      *(float4*)(o + base) = ov;
    }
  }
}

// ---------------------------------------------------------------------------
extern "C" void kernel_launch(void* const* d_in, const int* in_sizes, int n_in,
                              void* d_out, int out_size, void* d_ws, size_t ws_size,
                              hipStream_t stream) {
  const float* x1  = (const float*)d_in[0];
  const float* x2  = (const float*)d_in[1];
  const float* wq1 = (const float*)d_in[2];
  const float* bq1 = (const float*)d_in[3];
  const float* wk1 = (const float*)d_in[4];
  const float* bk1 = (const float*)d_in[5];
  const float* wv1 = (const float*)d_in[6];
  const float* bv1 = (const float*)d_in[7];
  const float* wq2 = (const float*)d_in[8];
  const float* bq2 = (const float*)d_in[9];
  const float* wk2 = (const float*)d_in[10];
  const float* bk2 = (const float*)d_in[11];
  const float* wv2 = (const float*)d_in[12];
  const float* bv2 = (const float*)d_in[13];
  const float* wd1 = (const float*)d_in[14];
  const float* bd1 = (const float*)d_in[15];
  const float* wd3 = (const float*)d_in[16];
  const float* bd3 = (const float*)d_in[17];
  const float* g1  = (const float*)d_in[18];
  const float* g2  = (const float*)d_in[19];
  float* out = (float*)d_out;

  // workspace layout (bytes)
  const size_t QB = (size_t)BB * NN * CKD * 2;   // 1 MB
  const size_t VB = (size_t)BB * NN * CC * 2;    // 8 MB
  const size_t RB = (size_t)BB * NN * CC * 4;    // 16 MB
  const size_t XB = (size_t)2 * BB * NN * CC * 2; // 16 MB
  char* base = (char*)d_ws;
  float* R1 = (float*)(base);
  float* R2 = (float*)(base + RB);
  unsigned short* Qp1 = (unsigned short*)(base + 2 * RB);
  unsigned short* Kp1 = (unsigned short*)(base + 2 * RB + QB);
  unsigned short* Qp2 = (unsigned short*)(base + 2 * RB + 2 * QB);
  unsigned short* Kp2 = (unsigned short*)(base + 2 * RB + 3 * QB);
  unsigned short* Vp1 = (unsigned short*)(base + 2 * RB + 4 * QB);
  unsigned short* Vp2 = (unsigned short*)(base + 2 * RB + 4 * QB + VB);
  unsigned short* Xp  = (unsigned short*)(base + 2 * RB + 4 * QB + 2 * VB);
  unsigned short* Wp  = (unsigned short*)(base + 2 * RB + 4 * QB + 2 * VB + XB);

  xpack_kernel<<<dim3(NN / 64, CC / 64, 2 * BB), 256, 0, stream>>>(x1, x2, Xp);
  wpack_kernel<<<dim3(CC * CC / 256), 256, 0, stream>>>(wd1, wd3, Wp);

  dim3 pgrid(NN / 64, 20, BB);
  proj_kernel<<<pgrid, 64, 0, stream>>>(x1, wq1, bq1, wk1, bk1, wv1, bv1, Qp1, Kp1, Vp1);
  proj_kernel<<<pgrid, 64, 0, stream>>>(x2, wq2, bq2, wk2, bk2, wv2, bv2, Qp2, Kp2, Vp2);

  conv_mfma_kernel<<<dim3(NN / 128, 2, 2 * BB), 256, 0, stream>>>(
      Xp, Wp, bd1, bd3, R1, R2);

  dim3 agrid(NN / 64, 2, BB);
  attn_kernel<<<agrid, 256, 0, stream>>>(Qp1, Kp1, Qp2, Kp2, Vp1, Vp2,
                                         R1, R2, x1, x2, g1, g2, out);
}

// Round 4
// 326.067 us; speedup vs baseline: 10.3724x; 1.7264x over previous
//
#include <hip/hip_runtime.h>
#include <hip/hip_bf16.h>

// Problem constants
#define CC 256      // channels
#define CKD 32      // q/k projection dim
#define NN 4096     // H*W
#define HH 64
#define WW 64
#define BB 4

typedef __attribute__((ext_vector_type(8))) short short8;   // 8 bf16 (4 VGPRs)
typedef __attribute__((ext_vector_type(4))) float floatx4;  // MFMA C/D frag

__device__ __forceinline__ unsigned f2bf(float f) {
  union { float f; unsigned u; } v; v.f = f;
  unsigned r = v.u + 0x7fffu + ((v.u >> 16) & 1u);   // RNE
  return r >> 16;
}

// ---------------------------------------------------------------------------
// Kernel 0a: pack x (fp32 [img][c][n]) -> Xp (bf16 [img][n][c], c contiguous)
// ---------------------------------------------------------------------------
__global__ __launch_bounds__(256) void xpack_kernel(
    const float* __restrict__ x1, const float* __restrict__ x2,
    unsigned short* __restrict__ Xp) {
  const int t = threadIdx.x;
  const int nb = blockIdx.x, cbk = blockIdx.y, img = blockIdx.z;
  const float* X = ((img >> 2) ? x2 : x1) + (size_t)(img & 3) * CC * NN;
  const int n0 = nb * 64, c0 = cbk * 64;
  __shared__ float tile[64][65];
  const int nl = t & 63, cl0 = t >> 6;
#pragma unroll
  for (int i = 0; i < 16; ++i)
    tile[cl0 + i * 4][nl] = X[(size_t)(c0 + cl0 + i * 4) * NN + n0 + nl];
  __syncthreads();
#pragma unroll
  for (int it = 0; it < 2; ++it) {
    int id = it * 256 + t;
    int nl2 = id >> 3, cc = id & 7;
    short8 v;
#pragma unroll
    for (int j = 0; j < 8; ++j) v[j] = (short)f2bf(tile[cc * 8 + j][nl2]);
    *(short8*)(Xp + (size_t)img * NN * CC + (size_t)(n0 + nl2) * CC + c0 + cc * 8) = v;
  }
}

// ---------------------------------------------------------------------------
// Kernel 0b: pack conv weights Wp[tap][o][c] (tap 9 = 1x1), QKV weights
// Wqkv[inp][o=320][c], and Bias[inp][320] (fp32).
// grid 256 x 256 threads; id = o*256+c for conv part.
// ---------------------------------------------------------------------------
__global__ __launch_bounds__(256) void wpack_kernel(
    const float* __restrict__ wd1, const float* __restrict__ wd3,
    const float* __restrict__ wq1, const float* __restrict__ wk1,
    const float* __restrict__ wv1,
    const float* __restrict__ wq2, const float* __restrict__ wk2,
    const float* __restrict__ wv2,
    const float* __restrict__ bq1, const float* __restrict__ bk1,
    const float* __restrict__ bv1,
    const float* __restrict__ bq2, const float* __restrict__ bk2,
    const float* __restrict__ bv2,
    unsigned short* __restrict__ Wp, unsigned short* __restrict__ Wqkv,
    float* __restrict__ Bias) {
  const int id = blockIdx.x * 256 + threadIdx.x;  // 0..65535
#pragma unroll
  for (int tap = 0; tap < 10; ++tap) {
    float v = (tap < 9) ? wd3[(size_t)id * 9 + tap] : wd1[id];
    Wp[(size_t)tap * (CC * CC) + id] = (unsigned short)f2bf(v);
  }
#pragma unroll
  for (int j = 0; j < 3; ++j) {
    int e = id + j * 65536;
    if (e < 2 * 320 * 256) {
      int inp = e / (320 * 256), rem = e % (320 * 256);
      int o = rem >> 8, c = rem & 255;
      float v;
      if (inp == 0)
        v = (o < 32) ? wq1[o * 256 + c]
            : (o < 64) ? wk1[(o - 32) * 256 + c] : wv1[(o - 64) * 256 + c];
      else
        v = (o < 32) ? wq2[o * 256 + c]
            : (o < 64) ? wk2[(o - 32) * 256 + c] : wv2[(o - 64) * 256 + c];
      Wqkv[e] = (unsigned short)f2bf(v);
    }
  }
  if (id < 640) {
    int inp = id / 320, o = id % 320;
    float v;
    if (inp == 0) v = (o < 32) ? bq1[o] : (o < 64) ? bk1[o - 32] : bv1[o - 64];
    else          v = (o < 32) ? bq2[o] : (o < 64) ? bk2[o - 32] : bv2[o - 64];
    Bias[id] = v;
  }
}

// ---------------------------------------------------------------------------
// Kernel 1: MFMA projections. GEMM: [64 pix] x [320 o] x [K=256 c] per block.
// A = Xp rows (direct global), B = Wqkv rows (direct global), no main-loop LDS.
// Epilogue: +bias, bf16, transpose via LDS tile[o][pix], emit Qp/Kp/Vp layouts:
//   Qp/Kp[b][n][32] (d contiguous), Vp[b][n>>3][c][n&7].
// grid (8 imgs, 64 pix-blocks) -> linear id % 8 = img (XCD-pinned).
// ---------------------------------------------------------------------------
__global__ __launch_bounds__(256) void proj_mfma_kernel(
    const unsigned short* __restrict__ Xp, const unsigned short* __restrict__ Wqkv,
    const float* __restrict__ Bias,
    unsigned short* __restrict__ Qp1, unsigned short* __restrict__ Kp1,
    unsigned short* __restrict__ Vp1,
    unsigned short* __restrict__ Qp2, unsigned short* __restrict__ Kp2,
    unsigned short* __restrict__ Vp2) {
  const int t = threadIdx.x;
  const int w = t >> 6, lane = t & 63;
  const int l15 = lane & 15, g = lane >> 4;
  const int img = blockIdx.x, pb = blockIdx.y;
  const int pix0 = pb * 64;
  const int inp = img >> 2, b = img & 3;
  const unsigned short* Xi = Xp + (size_t)img * NN * CC;
  const unsigned short* Wb = Wqkv + (size_t)inp * 320 * CC;
  const float* Bi = Bias + inp * 320;
  unsigned short* Qp = (inp ? Qp2 : Qp1) + (size_t)b * NN * CKD;
  unsigned short* Kp = (inp ? Kp2 : Kp1) + (size_t)b * NN * CKD;
  unsigned short* Vp = (inp ? Vp2 : Vp1) + (size_t)b * NN * CC;

  __shared__ unsigned short tile[320][72];   // [o][pix], stride 72 (16B-align ok)

  floatx4 acc[4][5];
#pragma unroll
  for (int mf = 0; mf < 4; ++mf)
#pragma unroll
    for (int nf = 0; nf < 5; ++nf) acc[mf][nf] = (floatx4){0.f, 0.f, 0.f, 0.f};
  const int o0w = w * 80;

#pragma unroll
  for (int cb = 0; cb < 8; ++cb) {
    short8 a[4], bfr[5];
#pragma unroll
    for (int mf = 0; mf < 4; ++mf)
      a[mf] = *(const short8*)(Xi + (size_t)(pix0 + mf * 16 + l15) * CC + cb * 32 + g * 8);
#pragma unroll
    for (int nf = 0; nf < 5; ++nf)
      bfr[nf] = *(const short8*)(Wb + (size_t)(o0w + nf * 16 + l15) * CC + cb * 32 + g * 8);
#pragma unroll
    for (int nf = 0; nf < 5; ++nf)
#pragma unroll
      for (int mf = 0; mf < 4; ++mf)
        acc[mf][nf] = __builtin_amdgcn_mfma_f32_16x16x32_bf16(
            a[mf], bfr[nf], acc[mf][nf], 0, 0, 0);
  }

  // bias + transposed LDS tile writes (b64: 4 consecutive pix per lane)
#pragma unroll
  for (int nf = 0; nf < 5; ++nf) {
    float bs = Bi[o0w + nf * 16 + l15];
#pragma unroll
    for (int mf = 0; mf < 4; ++mf) {
      uint2 pk;
      pk.x = f2bf(acc[mf][nf][0] + bs) | (f2bf(acc[mf][nf][1] + bs) << 16);
      pk.y = f2bf(acc[mf][nf][2] + bs) | (f2bf(acc[mf][nf][3] + bs) << 16);
      *(uint2*)&tile[o0w + nf * 16 + l15][mf * 16 + g * 4] = pk;
    }
  }
  __syncthreads();

  // Q/K: thread t -> pix = t>>2, chunk = t&3 (8 d's each)
  {
    const int pix = t >> 2, ch = t & 3;
    short8 vq, vk;
#pragma unroll
    for (int e = 0; e < 8; ++e) {
      vq[e] = (short)tile[ch * 8 + e][pix];
      vk[e] = (short)tile[32 + ch * 8 + e][pix];
    }
    *(short8*)(Qp + (size_t)(pix0 + pix) * CKD + ch * 8) = vq;
    *(short8*)(Kp + (size_t)(pix0 + pix) * CKD + ch * 8) = vk;
  }
  // V: iteration it = pix-group, thread t = channel c
#pragma unroll
  for (int it = 0; it < 8; ++it) {
    short8 vv = *(const short8*)&tile[64 + t][it * 8];
    *(short8*)(Vp + ((size_t)((pix0 >> 3) + it) * CC + t) * 8) = vv;
  }
}

// ---------------------------------------------------------------------------
// Kernel 2: implicit-GEMM MFMA conv (as R3, grid reordered for XCD locality)
// grid (2 ob, 8 img, 32 pb): id%8 = (ob + 2*img)%8 -> img pinned to <=2 XCDs.
// ---------------------------------------------------------------------------
__global__ __launch_bounds__(256) void conv_mfma_kernel(
    const unsigned short* __restrict__ Xp, const unsigned short* __restrict__ Wp,
    const float* __restrict__ bd1, const float* __restrict__ bd3,
    float* __restrict__ R1, float* __restrict__ R2) {
  const int t = threadIdx.x;
  const int w = t >> 6, lane = t & 63;
  const int l15 = lane & 15, g = lane >> 4;
  const int ob = blockIdx.x, img = blockIdx.y, pb = blockIdx.z;
  const int o0 = ob * 128, n0 = pb * 128, y0 = pb * 2;
  const int wm = w >> 1, wn = w & 1;

  const unsigned short* Xi = Xp + (size_t)img * NN * CC;
  float* R = ((img >> 2) ? R2 : R1) + (size_t)(img & 3) * CC * NN;

  __shared__ unsigned short xs[4][66][72];  // rows y0-1..y0+2, cols -1..64
  __shared__ unsigned short ws[128][72];

  floatx4 acc[4][4];
#pragma unroll
  for (int m = 0; m < 4; ++m)
#pragma unroll
    for (int n = 0; n < 4; ++n) acc[m][n] = (floatx4){0.f, 0.f, 0.f, 0.f};

  for (int cb = 0; cb < 4; ++cb) {
    const int c0 = cb * 64;
    __syncthreads();
#pragma unroll
    for (int it = 0; it < 9; ++it) {
      int id = it * 256 + t;
      if (id < 2112) {
        int r = id / 528, rem = id % 528;
        int col = rem >> 3, cc = rem & 7;
        int y = y0 - 1 + r, x = col - 1;
        short8 v = {0, 0, 0, 0, 0, 0, 0, 0};
        if (y >= 0 && y < HH && x >= 0 && x < WW)
          v = *(const short8*)(Xi + (size_t)(y * WW + x) * CC + c0 + cc * 8);
        *(short8*)&xs[r][col][cc * 8] = v;
      }
    }
    for (int tap = 0; tap < 10; ++tap) {
      __syncthreads();
#pragma unroll
      for (int it = 0; it < 4; ++it) {
        int id = it * 256 + t;
        int ol = id >> 3, cc = id & 7;
        *(short8*)&ws[ol][cc * 8] = *(const short8*)(
            Wp + (size_t)(tap * CC + o0 + ol) * CC + c0 + cc * 8);
      }
      __syncthreads();
      const int dy = (tap < 9) ? tap / 3 - 1 : 0;
      const int dx = (tap < 9) ? tap % 3 - 1 : 0;
      const int rrow = 1 + wn + dy;
#pragma unroll
      for (int ks = 0; ks < 2; ++ks) {
        short8 af[4], bf[4];
#pragma unroll
        for (int m = 0; m < 4; ++m)
          af[m] = *(const short8*)&ws[wm * 64 + m * 16 + l15][ks * 32 + g * 8];
#pragma unroll
        for (int n = 0; n < 4; ++n)
          bf[n] = *(const short8*)&xs[rrow][1 + n * 16 + l15 + dx][ks * 32 + g * 8];
#pragma unroll
        for (int m = 0; m < 4; ++m)
#pragma unroll
          for (int n = 0; n < 4; ++n)
            acc[m][n] = __builtin_amdgcn_mfma_f32_16x16x32_bf16(
                af[m], bf[n], acc[m][n], 0, 0, 0);
      }
    }
  }

#pragma unroll
  for (int m = 0; m < 4; ++m) {
    int ob2 = o0 + wm * 64 + m * 16 + g * 4;
    float bs[4];
#pragma unroll
    for (int r = 0; r < 4; ++r) bs[r] = bd1[ob2 + r] + bd3[ob2 + r];
#pragma unroll
    for (int n = 0; n < 4; ++n) {
      int pix = n0 + wn * 64 + n * 16 + l15;
#pragma unroll
      for (int r = 0; r < 4; ++r)
        R[(size_t)(ob2 + r) * NN + pix] = acc[m][n][r] + bs[r];
    }
  }
}

// ---------------------------------------------------------------------------
// Kernel 3: one-pass MFMA flash attention (constant-shift softmax) + epilogue.
// grid (2 att, 4 b, 64 i-blocks): id%8 = att+2b -> (att,b) pinned to one XCD,
// so its V slice (2MB) lives in that XCD's L2.
// GEMM1 transposed (A=K, B=Q): lane owns 4 consecutive j -> ds_write_b64 P.
// K/V register double-buffer prefetch; single barrier per tile (P dbuf).
// ---------------------------------------------------------------------------
__global__ __launch_bounds__(256, 2) void attn_kernel(
    const unsigned short* __restrict__ Qp1, const unsigned short* __restrict__ Kp1,
    const unsigned short* __restrict__ Qp2, const unsigned short* __restrict__ Kp2,
    const unsigned short* __restrict__ Vp1, const unsigned short* __restrict__ Vp2,
    const float* __restrict__ R1, const float* __restrict__ R2,
    const float* __restrict__ x1, const float* __restrict__ x2,
    const float* __restrict__ g1, const float* __restrict__ g2,
    float* __restrict__ out) {
  const int t = threadIdx.x;
  const int w = t >> 6, lane = t & 63;
  const int l15 = lane & 15, g = lane >> 4;
  const int att = blockIdx.x, b = blockIdx.y;
  const int i0 = blockIdx.z * 64;

  const unsigned short *Qp, *Kp, *Vp; const float *R, *x; float gamma; float* o;
  if (att == 0) { Qp = Qp1; Kp = Kp2; Vp = Vp2; R = R1; x = x1; gamma = g1[0]; o = out; }
  else          { Qp = Qp2; Kp = Kp1; Vp = Vp1; R = R2; x = x2; gamma = g2[0];
                  o = out + (size_t)BB * CC * NN; }
  Qp += (size_t)b * NN * CKD; Kp += (size_t)b * NN * CKD; Vp += (size_t)b * NN * CC;
  R += (size_t)b * CC * NN; x += (size_t)b * CC * NN; o += (size_t)b * CC * NN;

  __shared__ unsigned short p_s[2][64][72];
  __shared__ float l_s[64];

  // Q B-frag (held whole kernel): n = i = i0 + w*16 + l15, k = d = g*8..
  short8 bq = *(const short8*)(Qp + (size_t)(i0 + w * 16 + l15) * CKD + g * 8);

  floatx4 acc[4][4];
#pragma unroll
  for (int a = 0; a < 4; ++a)
#pragma unroll
    for (int c = 0; c < 4; ++c) acc[a][c] = (floatx4){0.f, 0.f, 0.f, 0.f};
  float l_acc = 0.f;

  short8 kr[2][4], vr[2][8];
#pragma unroll
  for (int js = 0; js < 4; ++js)
    kr[0][js] = *(const short8*)(Kp + (size_t)(js * 16 + l15) * CKD + g * 8);
#pragma unroll
  for (int ks = 0; ks < 2; ++ks)
#pragma unroll
    for (int cs = 0; cs < 4; ++cs)
      vr[0][ks * 4 + cs] = *(const short8*)(Vp +
          ((size_t)(ks * 4 + g) * CC + (w * 64 + cs * 16 + l15)) * 8);

#pragma unroll 2
  for (int jt = 0; jt < NN / 64; ++jt) {
    const int cur = jt & 1, nxt = cur ^ 1;
    if (jt + 1 < NN / 64) {
      const size_t j0n = (size_t)(jt + 1) * 64;
#pragma unroll
      for (int js = 0; js < 4; ++js)
        kr[nxt][js] = *(const short8*)(Kp + (j0n + js * 16 + l15) * CKD + g * 8);
#pragma unroll
      for (int ks = 0; ks < 2; ++ks)
#pragma unroll
        for (int cs = 0; cs < 4; ++cs)
          vr[nxt][ks * 4 + cs] = *(const short8*)(Vp +
              (((j0n >> 3) + ks * 4 + g) * CC + (w * 64 + cs * 16 + l15)) * 8);
    }
    // GEMM1 (S^T): lane holds j = js*16 + g*4 + r, i = w*16 + l15
#pragma unroll
    for (int js = 0; js < 4; ++js) {
      floatx4 z = {0.f, 0.f, 0.f, 0.f};
      floatx4 s = __builtin_amdgcn_mfma_f32_16x16x32_bf16(kr[cur][js], bq, z, 0, 0, 0);
      float p0 = __expf(s[0] - 16.f);
      float p1 = __expf(s[1] - 16.f);
      float p2 = __expf(s[2] - 16.f);
      float p3 = __expf(s[3] - 16.f);
      l_acc += (p0 + p1) + (p2 + p3);
      uint2 pk;
      pk.x = f2bf(p0) | (f2bf(p1) << 16);
      pk.y = f2bf(p2) | (f2bf(p3) << 16);
      *(uint2*)&p_s[cur][w * 16 + l15][js * 16 + g * 4] = pk;
    }
    __syncthreads();
    // GEMM2: acc += P * V^T
#pragma unroll
    for (int ks = 0; ks < 2; ++ks) {
      short8 ap[4];
#pragma unroll
      for (int isub = 0; isub < 4; ++isub)
        ap[isub] = *(const short8*)&p_s[cur][isub * 16 + l15][ks * 32 + g * 8];
#pragma unroll
      for (int cs = 0; cs < 4; ++cs)
#pragma unroll
        for (int isub = 0; isub < 4; ++isub)
          acc[isub][cs] = __builtin_amdgcn_mfma_f32_16x16x32_bf16(
              ap[isub], vr[cur][ks * 4 + cs], acc[isub][cs], 0, 0, 0);
    }
  }

  // l: reduce across g (lane bits 4,5); all j covered per (i) after union
  l_acc += __shfl_xor(l_acc, 16);
  l_acc += __shfl_xor(l_acc, 32);
  if (g == 0) l_s[w * 16 + l15] = l_acc;
  __syncthreads();

  // epilogue: out[c][i] = x + gamma*(acc/l + R)
#pragma unroll
  for (int isub = 0; isub < 4; ++isub) {
    float linv[4];
#pragma unroll
    for (int r = 0; r < 4; ++r) linv[r] = 1.f / l_s[isub * 16 + g * 4 + r];
#pragma unroll
    for (int cs = 0; cs < 4; ++cs) {
      int c = w * 64 + cs * 16 + l15;
      size_t base = (size_t)c * NN + i0 + isub * 16 + g * 4;
      float4 xr = *(const float4*)(x + base);
      float4 rr = *(const float4*)(R + base);
      float4 ov;
      ov.x = xr.x + gamma * (acc[isub][cs][0] * linv[0] + rr.x);
      ov.y = xr.y + gamma * (acc[isub][cs][1] * linv[1] + rr.y);
      ov.z = xr.z + gamma * (acc[isub][cs][2] * linv[2] + rr.z);
      ov.w = xr.w + gamma * (acc[isub][cs][3] * linv[3] + rr.w);
      *(float4*)(o + base) = ov;
    }
  }
}

// ---------------------------------------------------------------------------
extern "C" void kernel_launch(void* const* d_in, const int* in_sizes, int n_in,
                              void* d_out, int out_size, void* d_ws, size_t ws_size,
                              hipStream_t stream) {
  const float* x1  = (const float*)d_in[0];
  const float* x2  = (const float*)d_in[1];
  const float* wq1 = (const float*)d_in[2];
  const float* bq1 = (const float*)d_in[3];
  const float* wk1 = (const float*)d_in[4];
  const float* bk1 = (const float*)d_in[5];
  const float* wv1 = (const float*)d_in[6];
  const float* bv1 = (const float*)d_in[7];
  const float* wq2 = (const float*)d_in[8];
  const float* bq2 = (const float*)d_in[9];
  const float* wk2 = (const float*)d_in[10];
  const float* bk2 = (const float*)d_in[11];
  const float* wv2 = (const float*)d_in[12];
  const float* bv2 = (const float*)d_in[13];
  const float* wd1 = (const float*)d_in[14];
  const float* bd1 = (const float*)d_in[15];
  const float* wd3 = (const float*)d_in[16];
  const float* bd3 = (const float*)d_in[17];
  const float* g1  = (const float*)d_in[18];
  const float* g2  = (const float*)d_in[19];
  float* out = (float*)d_out;

  // workspace layout (bytes)
  const size_t QB = (size_t)BB * NN * CKD * 2;     // 1 MB
  const size_t VB = (size_t)BB * NN * CC * 2;      // 8 MB
  const size_t RB = (size_t)BB * NN * CC * 4;      // 16 MB
  const size_t XB = (size_t)2 * BB * NN * CC * 2;  // 16 MB
  const size_t WPB = (size_t)10 * CC * CC * 2;     // 1.31 MB
  const size_t WQB = (size_t)2 * 320 * CC * 2;     // 320 KB
  char* base = (char*)d_ws;
  float* R1 = (float*)(base);
  float* R2 = (float*)(base + RB);
  unsigned short* Qp1 = (unsigned short*)(base + 2 * RB);
  unsigned short* Kp1 = (unsigned short*)(base + 2 * RB + QB);
  unsigned short* Qp2 = (unsigned short*)(base + 2 * RB + 2 * QB);
  unsigned short* Kp2 = (unsigned short*)(base + 2 * RB + 3 * QB);
  unsigned short* Vp1 = (unsigned short*)(base + 2 * RB + 4 * QB);
  unsigned short* Vp2 = (unsigned short*)(base + 2 * RB + 4 * QB + VB);
  unsigned short* Xp  = (unsigned short*)(base + 2 * RB + 4 * QB + 2 * VB);
  unsigned short* Wp  = (unsigned short*)(base + 2 * RB + 4 * QB + 2 * VB + XB);
  unsigned short* Wqkv = (unsigned short*)(base + 2 * RB + 4 * QB + 2 * VB + XB + WPB);
  float* Bias = (float*)(base + 2 * RB + 4 * QB + 2 * VB + XB + WPB + WQB);

  xpack_kernel<<<dim3(NN / 64, CC / 64, 2 * BB), 256, 0, stream>>>(x1, x2, Xp);
  wpack_kernel<<<dim3(CC * CC / 256), 256, 0, stream>>>(
      wd1, wd3, wq1, wk1, wv1, wq2, wk2, wv2,
      bq1, bk1, bv1, bq2, bk2, bv2, Wp, Wqkv, Bias);

  proj_mfma_kernel<<<dim3(2 * BB, NN / 64), 256, 0, stream>>>(
      Xp, Wqkv, Bias, Qp1, Kp1, Vp1, Qp2, Kp2, Vp2);

  conv_mfma_kernel<<<dim3(2, 2 * BB, NN / 128), 256, 0, stream>>>(
      Xp, Wp, bd1, bd3, R1, R2);

  attn_kernel<<<dim3(2, BB, NN / 64), 256, 0, stream>>>(
      Qp1, Kp1, Qp2, Kp2, Vp1, Vp2, R1, R2, x1, x2, g1, g2, out);
}

// Round 5
// 316.871 us; speedup vs baseline: 10.6734x; 1.0290x over previous
//
#include <hip/hip_runtime.h>
#include <hip/hip_bf16.h>

// Problem constants
#define CC 256      // channels
#define CKD 32      // q/k projection dim
#define NN 4096     // H*W
#define HH 64
#define WW 64
#define BB 4

#define LOG2E 1.44269504088896f
#define EXPSHIFT 23.0831203874f   // 16 * LOG2E

typedef __attribute__((ext_vector_type(8))) short short8;   // 8 bf16 (4 VGPRs)
typedef __attribute__((ext_vector_type(4))) float floatx4;  // MFMA C/D frag

__device__ __forceinline__ unsigned f2bf(float f) {
  union { float f; unsigned u; } v; v.f = f;
  unsigned r = v.u + 0x7fffu + ((v.u >> 16) & 1u);   // RNE
  return r >> 16;
}
__device__ __forceinline__ unsigned short f2bf_fast(float f) {
  return (unsigned short)((__float_as_uint(f) + 0x8000u) >> 16);  // round, cheap
}
__device__ __forceinline__ float fast_exp2(float x) {
#if __has_builtin(__builtin_amdgcn_exp2f)
  return __builtin_amdgcn_exp2f(x);
#else
  return __expf(x * 0.693147181f);
#endif
}

// ---------------------------------------------------------------------------
// Kernel 0a: pack x (fp32 [img][c][n]) -> Xp (bf16 [img][n][c], c contiguous)
// ---------------------------------------------------------------------------
__global__ __launch_bounds__(256) void xpack_kernel(
    const float* __restrict__ x1, const float* __restrict__ x2,
    unsigned short* __restrict__ Xp) {
  const int t = threadIdx.x;
  const int nb = blockIdx.x, cbk = blockIdx.y, img = blockIdx.z;
  const float* X = ((img >> 2) ? x2 : x1) + (size_t)(img & 3) * CC * NN;
  const int n0 = nb * 64, c0 = cbk * 64;
  __shared__ float tile[64][65];
  const int nl = t & 63, cl0 = t >> 6;
#pragma unroll
  for (int i = 0; i < 16; ++i)
    tile[cl0 + i * 4][nl] = X[(size_t)(c0 + cl0 + i * 4) * NN + n0 + nl];
  __syncthreads();
#pragma unroll
  for (int it = 0; it < 2; ++it) {
    int id = it * 256 + t;
    int nl2 = id >> 3, cc = id & 7;
    short8 v;
#pragma unroll
    for (int j = 0; j < 8; ++j) v[j] = (short)f2bf(tile[cc * 8 + j][nl2]);
    *(short8*)(Xp + (size_t)img * NN * CC + (size_t)(n0 + nl2) * CC + c0 + cc * 8) = v;
  }
}

// ---------------------------------------------------------------------------
// Kernel 0b: pack conv weights Wp[tap][o][c] (tap 9 = 1x1), QKV weights
// Wqkv[inp][o=320][c] (q rows scaled by log2e), Bias[inp][320] (fp32, q scaled).
// ---------------------------------------------------------------------------
__global__ __launch_bounds__(256) void wpack_kernel(
    const float* __restrict__ wd1, const float* __restrict__ wd3,
    const float* __restrict__ wq1, const float* __restrict__ wk1,
    const float* __restrict__ wv1,
    const float* __restrict__ wq2, const float* __restrict__ wk2,
    const float* __restrict__ wv2,
    const float* __restrict__ bq1, const float* __restrict__ bk1,
    const float* __restrict__ bv1,
    const float* __restrict__ bq2, const float* __restrict__ bk2,
    const float* __restrict__ bv2,
    unsigned short* __restrict__ Wp, unsigned short* __restrict__ Wqkv,
    float* __restrict__ Bias) {
  const int id = blockIdx.x * 256 + threadIdx.x;  // 0..65535
#pragma unroll
  for (int tap = 0; tap < 10; ++tap) {
    float v = (tap < 9) ? wd3[(size_t)id * 9 + tap] : wd1[id];
    Wp[(size_t)tap * (CC * CC) + id] = (unsigned short)f2bf(v);
  }
#pragma unroll
  for (int j = 0; j < 3; ++j) {
    int e = id + j * 65536;
    if (e < 2 * 320 * 256) {
      int inp = e / (320 * 256), rem = e % (320 * 256);
      int o = rem >> 8, c = rem & 255;
      float v;
      if (inp == 0)
        v = (o < 32) ? wq1[o * 256 + c] * LOG2E
            : (o < 64) ? wk1[(o - 32) * 256 + c] : wv1[(o - 64) * 256 + c];
      else
        v = (o < 32) ? wq2[o * 256 + c] * LOG2E
            : (o < 64) ? wk2[(o - 32) * 256 + c] : wv2[(o - 64) * 256 + c];
      Wqkv[e] = (unsigned short)f2bf(v);
    }
  }
  if (id < 640) {
    int inp = id / 320, o = id % 320;
    float v;
    if (inp == 0) v = (o < 32) ? bq1[o] * LOG2E
                      : (o < 64) ? bk1[o - 32] : bv1[o - 64];
    else          v = (o < 32) ? bq2[o] * LOG2E
                      : (o < 64) ? bk2[o - 32] : bv2[o - 64];
    Bias[id] = v;
  }
}

// ---------------------------------------------------------------------------
// Kernel 1: MFMA projections. GEMM: [64 pix] x [320 o] x [K=256 c] per block.
// ---------------------------------------------------------------------------
__global__ __launch_bounds__(256) void proj_mfma_kernel(
    const unsigned short* __restrict__ Xp, const unsigned short* __restrict__ Wqkv,
    const float* __restrict__ Bias,
    unsigned short* __restrict__ Qp1, unsigned short* __restrict__ Kp1,
    unsigned short* __restrict__ Vp1,
    unsigned short* __restrict__ Qp2, unsigned short* __restrict__ Kp2,
    unsigned short* __restrict__ Vp2) {
  const int t = threadIdx.x;
  const int w = t >> 6, lane = t & 63;
  const int l15 = lane & 15, g = lane >> 4;
  const int img = blockIdx.x, pb = blockIdx.y;
  const int pix0 = pb * 64;
  const int inp = img >> 2, b = img & 3;
  const unsigned short* Xi = Xp + (size_t)img * NN * CC;
  const unsigned short* Wb = Wqkv + (size_t)inp * 320 * CC;
  const float* Bi = Bias + inp * 320;
  unsigned short* Qp = (inp ? Qp2 : Qp1) + (size_t)b * NN * CKD;
  unsigned short* Kp = (inp ? Kp2 : Kp1) + (size_t)b * NN * CKD;
  unsigned short* Vp = (inp ? Vp2 : Vp1) + (size_t)b * NN * CC;

  __shared__ unsigned short tile[320][72];   // [o][pix]

  floatx4 acc[4][5];
#pragma unroll
  for (int mf = 0; mf < 4; ++mf)
#pragma unroll
    for (int nf = 0; nf < 5; ++nf) acc[mf][nf] = (floatx4){0.f, 0.f, 0.f, 0.f};
  const int o0w = w * 80;

#pragma unroll
  for (int cb = 0; cb < 8; ++cb) {
    short8 a[4], bfr[5];
#pragma unroll
    for (int mf = 0; mf < 4; ++mf)
      a[mf] = *(const short8*)(Xi + (size_t)(pix0 + mf * 16 + l15) * CC + cb * 32 + g * 8);
#pragma unroll
    for (int nf = 0; nf < 5; ++nf)
      bfr[nf] = *(const short8*)(Wb + (size_t)(o0w + nf * 16 + l15) * CC + cb * 32 + g * 8);
#pragma unroll
    for (int nf = 0; nf < 5; ++nf)
#pragma unroll
      for (int mf = 0; mf < 4; ++mf)
        acc[mf][nf] = __builtin_amdgcn_mfma_f32_16x16x32_bf16(
            a[mf], bfr[nf], acc[mf][nf], 0, 0, 0);
  }

#pragma unroll
  for (int nf = 0; nf < 5; ++nf) {
    float bs = Bi[o0w + nf * 16 + l15];
#pragma unroll
    for (int mf = 0; mf < 4; ++mf) {
      uint2 pk;
      pk.x = f2bf(acc[mf][nf][0] + bs) | (f2bf(acc[mf][nf][1] + bs) << 16);
      pk.y = f2bf(acc[mf][nf][2] + bs) | (f2bf(acc[mf][nf][3] + bs) << 16);
      *(uint2*)&tile[o0w + nf * 16 + l15][mf * 16 + g * 4] = pk;
    }
  }
  __syncthreads();

  {
    const int pix = t >> 2, ch = t & 3;
    short8 vq, vk;
#pragma unroll
    for (int e = 0; e < 8; ++e) {
      vq[e] = (short)tile[ch * 8 + e][pix];
      vk[e] = (short)tile[32 + ch * 8 + e][pix];
    }
    *(short8*)(Qp + (size_t)(pix0 + pix) * CKD + ch * 8) = vq;
    *(short8*)(Kp + (size_t)(pix0 + pix) * CKD + ch * 8) = vk;
  }
#pragma unroll
  for (int it = 0; it < 8; ++it) {
    short8 vv = *(const short8*)&tile[64 + t][it * 8];
    *(short8*)(Vp + ((size_t)((pix0 >> 3) + it) * CC + t) * 8) = vv;
  }
}

// ---------------------------------------------------------------------------
// Kernel 2: implicit-GEMM MFMA conv. Weights now read DIRECTLY from global
// (L2-hot, per-wave private A-frags) — no ws LDS, no per-tap barriers.
// xs (pixel+halo tile) stays in LDS (shared across waves). R output bf16.
// grid (2 ob, 8 img, 32 pb).
// ---------------------------------------------------------------------------
__global__ __launch_bounds__(256, 2) void conv_mfma_kernel(
    const unsigned short* __restrict__ Xp, const unsigned short* __restrict__ Wp,
    const float* __restrict__ bd1, const float* __restrict__ bd3,
    unsigned short* __restrict__ R1, unsigned short* __restrict__ R2) {
  const int t = threadIdx.x;
  const int w = t >> 6, lane = t & 63;
  const int l15 = lane & 15, g = lane >> 4;
  const int ob = blockIdx.x, img = blockIdx.y, pb = blockIdx.z;
  const int o0 = ob * 128, n0 = pb * 128, y0 = pb * 2;
  const int wm = w >> 1, wn = w & 1;

  const unsigned short* Xi = Xp + (size_t)img * NN * CC;
  unsigned short* R = ((img >> 2) ? R2 : R1) + (size_t)(img & 3) * CC * NN;

  __shared__ unsigned short xs[4][66][72];  // rows y0-1..y0+2, cols -1..64

  floatx4 acc[4][4];
#pragma unroll
  for (int m = 0; m < 4; ++m)
#pragma unroll
    for (int n = 0; n < 4; ++n) acc[m][n] = (floatx4){0.f, 0.f, 0.f, 0.f};

  for (int cb = 0; cb < 4; ++cb) {
    const int c0 = cb * 64;
    __syncthreads();   // previous iter's xs reads complete
#pragma unroll
    for (int it = 0; it < 9; ++it) {
      int id = it * 256 + t;
      if (id < 2112) {                 // 4*66*8 16B-chunks
        int r = id / 528, rem = id % 528;
        int col = rem >> 3, cc = rem & 7;
        int y = y0 - 1 + r, x = col - 1;
        short8 v = {0, 0, 0, 0, 0, 0, 0, 0};
        if (y >= 0 && y < HH && x >= 0 && x < WW)
          v = *(const short8*)(Xi + (size_t)(y * WW + x) * CC + c0 + cc * 8);
        *(short8*)&xs[r][col][cc * 8] = v;
      }
    }
    __syncthreads();   // xs ready
#pragma unroll
    for (int tap = 0; tap < 10; ++tap) {
      const int dy = (tap < 9) ? tap / 3 - 1 : 0;
      const int dx = (tap < 9) ? tap % 3 - 1 : 0;
      const int rrow = 1 + wn + dy;
      const unsigned short* wrow =
          Wp + (size_t)(tap * CC + o0 + wm * 64 + l15) * CC + c0 + g * 8;
#pragma unroll
      for (int ks = 0; ks < 2; ++ks) {
        short8 af[4], bf[4];
#pragma unroll
        for (int m = 0; m < 4; ++m)
          af[m] = *(const short8*)(wrow + (size_t)(m * 16) * CC + ks * 32);
#pragma unroll
        for (int n = 0; n < 4; ++n)
          bf[n] = *(const short8*)&xs[rrow][1 + n * 16 + l15 + dx][ks * 32 + g * 8];
#pragma unroll
        for (int m = 0; m < 4; ++m)
#pragma unroll
          for (int n = 0; n < 4; ++n)
            acc[m][n] = __builtin_amdgcn_mfma_f32_16x16x32_bf16(
                af[m], bf[n], acc[m][n], 0, 0, 0);
      }
    }
  }

  // epilogue: R[o][pix] = bf16(acc + bd1[o] + bd3[o])
#pragma unroll
  for (int m = 0; m < 4; ++m) {
    int ob2 = o0 + wm * 64 + m * 16 + g * 4;
    float bs[4];
#pragma unroll
    for (int r = 0; r < 4; ++r) bs[r] = bd1[ob2 + r] + bd3[ob2 + r];
#pragma unroll
    for (int n = 0; n < 4; ++n) {
      int pix = n0 + wn * 64 + n * 16 + l15;
#pragma unroll
      for (int r = 0; r < 4; ++r)
        R[(size_t)(ob2 + r) * NN + pix] = f2bf_fast(acc[m][n][r] + bs[r]);
    }
  }
}

// ---------------------------------------------------------------------------
// Kernel 3: one-pass MFMA flash attention (2^x-domain softmax, shift folded
// into MFMA accumulator init) + fused epilogue. R read as bf16.
// grid (2 att, 4 b, 64 i-blocks): id%8 = att+2b -> XCD-pinned V slice.
// ---------------------------------------------------------------------------
__global__ __launch_bounds__(256, 2) void attn_kernel(
    const unsigned short* __restrict__ Qp1, const unsigned short* __restrict__ Kp1,
    const unsigned short* __restrict__ Qp2, const unsigned short* __restrict__ Kp2,
    const unsigned short* __restrict__ Vp1, const unsigned short* __restrict__ Vp2,
    const unsigned short* __restrict__ R1, const unsigned short* __restrict__ R2,
    const float* __restrict__ x1, const float* __restrict__ x2,
    const float* __restrict__ g1, const float* __restrict__ g2,
    float* __restrict__ out) {
  const int t = threadIdx.x;
  const int w = t >> 6, lane = t & 63;
  const int l15 = lane & 15, g = lane >> 4;
  const int att = blockIdx.x, b = blockIdx.y;
  const int i0 = blockIdx.z * 64;

  const unsigned short *Qp, *Kp, *Vp, *Rb; const float *x; float gamma; float* o;
  if (att == 0) { Qp = Qp1; Kp = Kp2; Vp = Vp2; Rb = R1; x = x1; gamma = g1[0]; o = out; }
  else          { Qp = Qp2; Kp = Kp1; Vp = Vp1; Rb = R2; x = x2; gamma = g2[0];
                  o = out + (size_t)BB * CC * NN; }
  Qp += (size_t)b * NN * CKD; Kp += (size_t)b * NN * CKD; Vp += (size_t)b * NN * CC;
  Rb += (size_t)b * CC * NN; x += (size_t)b * CC * NN; o += (size_t)b * CC * NN;

  __shared__ unsigned short p_s[2][64][72];
  __shared__ float l_s[64];

  // Q B-frag (held whole kernel); Q is pre-scaled by log2e
  short8 bq = *(const short8*)(Qp + (size_t)(i0 + w * 16 + l15) * CKD + g * 8);

  floatx4 acc[4][4];
#pragma unroll
  for (int a = 0; a < 4; ++a)
#pragma unroll
    for (int c = 0; c < 4; ++c) acc[a][c] = (floatx4){0.f, 0.f, 0.f, 0.f};
  float l_acc = 0.f;
  const floatx4 zinit = {-EXPSHIFT, -EXPSHIFT, -EXPSHIFT, -EXPSHIFT};

  short8 kr[2][4], vr[2][8];
#pragma unroll
  for (int js = 0; js < 4; ++js)
    kr[0][js] = *(const short8*)(Kp + (size_t)(js * 16 + l15) * CKD + g * 8);
#pragma unroll
  for (int ks = 0; ks < 2; ++ks)
#pragma unroll
    for (int cs = 0; cs < 4; ++cs)
      vr[0][ks * 4 + cs] = *(const short8*)(Vp +
          ((size_t)(ks * 4 + g) * CC + (w * 64 + cs * 16 + l15)) * 8);

#pragma unroll 2
  for (int jt = 0; jt < NN / 64; ++jt) {
    const int cur = jt & 1, nxt = cur ^ 1;
    if (jt + 1 < NN / 64) {
      const size_t j0n = (size_t)(jt + 1) * 64;
#pragma unroll
      for (int js = 0; js < 4; ++js)
        kr[nxt][js] = *(const short8*)(Kp + (j0n + js * 16 + l15) * CKD + g * 8);
#pragma unroll
      for (int ks = 0; ks < 2; ++ks)
#pragma unroll
        for (int cs = 0; cs < 4; ++cs)
          vr[nxt][ks * 4 + cs] = *(const short8*)(Vp +
              (((j0n >> 3) + ks * 4 + g) * CC + (w * 64 + cs * 16 + l15)) * 8);
    }
    // GEMM1 (S^T), shift pre-folded into accumulator: p = 2^(s)
#pragma unroll
    for (int js = 0; js < 4; ++js) {
      floatx4 s = __builtin_amdgcn_mfma_f32_16x16x32_bf16(kr[cur][js], bq, zinit, 0, 0, 0);
      float p0 = fast_exp2(s[0]);
      float p1 = fast_exp2(s[1]);
      float p2 = fast_exp2(s[2]);
      float p3 = fast_exp2(s[3]);
      l_acc += (p0 + p1) + (p2 + p3);
      unsigned u0 = __float_as_uint(p0) + 0x8000u;
      unsigned u1 = __float_as_uint(p1) + 0x8000u;
      unsigned u2 = __float_as_uint(p2) + 0x8000u;
      unsigned u3 = __float_as_uint(p3) + 0x8000u;
      uint2 pk;
      pk.x = __builtin_amdgcn_perm(u1, u0, 0x07060302u);
      pk.y = __builtin_amdgcn_perm(u3, u2, 0x07060302u);
      *(uint2*)&p_s[cur][w * 16 + l15][js * 16 + g * 4] = pk;
    }
    __syncthreads();
    // GEMM2: acc += P * V^T
#pragma unroll
    for (int ks = 0; ks < 2; ++ks) {
      short8 ap[4];
#pragma unroll
      for (int isub = 0; isub < 4; ++isub)
        ap[isub] = *(const short8*)&p_s[cur][isub * 16 + l15][ks * 32 + g * 8];
#pragma unroll
      for (int cs = 0; cs < 4; ++cs)
#pragma unroll
        for (int isub = 0; isub < 4; ++isub)
          acc[isub][cs] = __builtin_amdgcn_mfma_f32_16x16x32_bf16(
              ap[isub], vr[cur][ks * 4 + cs], acc[isub][cs], 0, 0, 0);
    }
  }

  // l: reduce across g (lane bits 4,5)
  l_acc += __shfl_xor(l_acc, 16);
  l_acc += __shfl_xor(l_acc, 32);
  if (g == 0) l_s[w * 16 + l15] = l_acc;
  __syncthreads();

  // epilogue: out[c][i] = x + gamma*(acc/l + R)
#pragma unroll
  for (int isub = 0; isub < 4; ++isub) {
    float linv[4];
#pragma unroll
    for (int r = 0; r < 4; ++r) linv[r] = 1.f / l_s[isub * 16 + g * 4 + r];
#pragma unroll
    for (int cs = 0; cs < 4; ++cs) {
      int c = w * 64 + cs * 16 + l15;
      size_t base = (size_t)c * NN + i0 + isub * 16 + g * 4;
      float4 xr = *(const float4*)(x + base);
      uint2 rr = *(const uint2*)(Rb + base);
      float r0 = __uint_as_float(rr.x << 16);
      float r1 = __uint_as_float(rr.x & 0xffff0000u);
      float r2 = __uint_as_float(rr.y << 16);
      float r3 = __uint_as_float(rr.y & 0xffff0000u);
      float4 ov;
      ov.x = xr.x + gamma * (acc[isub][cs][0] * linv[0] + r0);
      ov.y = xr.y + gamma * (acc[isub][cs][1] * linv[1] + r1);
      ov.z = xr.z + gamma * (acc[isub][cs][2] * linv[2] + r2);
      ov.w = xr.w + gamma * (acc[isub][cs][3] * linv[3] + r3);
      *(float4*)(o + base) = ov;
    }
  }
}

// ---------------------------------------------------------------------------
extern "C" void kernel_launch(void* const* d_in, const int* in_sizes, int n_in,
                              void* d_out, int out_size, void* d_ws, size_t ws_size,
                              hipStream_t stream) {
  const float* x1  = (const float*)d_in[0];
  const float* x2  = (const float*)d_in[1];
  const float* wq1 = (const float*)d_in[2];
  const float* bq1 = (const float*)d_in[3];
  const float* wk1 = (const float*)d_in[4];
  const float* bk1 = (const float*)d_in[5];
  const float* wv1 = (const float*)d_in[6];
  const float* bv1 = (const float*)d_in[7];
  const float* wq2 = (const float*)d_in[8];
  const float* bq2 = (const float*)d_in[9];
  const float* wk2 = (const float*)d_in[10];
  const float* bk2 = (const float*)d_in[11];
  const float* wv2 = (const float*)d_in[12];
  const float* bv2 = (const float*)d_in[13];
  const float* wd1 = (const float*)d_in[14];
  const float* bd1 = (const float*)d_in[15];
  const float* wd3 = (const float*)d_in[16];
  const float* bd3 = (const float*)d_in[17];
  const float* g1  = (const float*)d_in[18];
  const float* g2  = (const float*)d_in[19];
  float* out = (float*)d_out;

  // workspace layout (bytes)
  const size_t QB = (size_t)BB * NN * CKD * 2;     // 1 MB
  const size_t VB = (size_t)BB * NN * CC * 2;      // 8 MB
  const size_t RB = (size_t)BB * NN * CC * 2;      // 8 MB (bf16 now)
  const size_t XB = (size_t)2 * BB * NN * CC * 2;  // 16 MB
  const size_t WPB = (size_t)10 * CC * CC * 2;     // 1.31 MB
  const size_t WQB = (size_t)2 * 320 * CC * 2;     // 320 KB
  char* base = (char*)d_ws;
  unsigned short* R1 = (unsigned short*)(base);
  unsigned short* R2 = (unsigned short*)(base + RB);
  unsigned short* Qp1 = (unsigned short*)(base + 2 * RB);
  unsigned short* Kp1 = (unsigned short*)(base + 2 * RB + QB);
  unsigned short* Qp2 = (unsigned short*)(base + 2 * RB + 2 * QB);
  unsigned short* Kp2 = (unsigned short*)(base + 2 * RB + 3 * QB);
  unsigned short* Vp1 = (unsigned short*)(base + 2 * RB + 4 * QB);
  unsigned short* Vp2 = (unsigned short*)(base + 2 * RB + 4 * QB + VB);
  unsigned short* Xp  = (unsigned short*)(base + 2 * RB + 4 * QB + 2 * VB);
  unsigned short* Wp  = (unsigned short*)(base + 2 * RB + 4 * QB + 2 * VB + XB);
  unsigned short* Wqkv = (unsigned short*)(base + 2 * RB + 4 * QB + 2 * VB + XB + WPB);
  float* Bias = (float*)(base + 2 * RB + 4 * QB + 2 * VB + XB + WPB + WQB);

  xpack_kernel<<<dim3(NN / 64, CC / 64, 2 * BB), 256, 0, stream>>>(x1, x2, Xp);
  wpack_kernel<<<dim3(CC * CC / 256), 256, 0, stream>>>(
      wd1, wd3, wq1, wk1, wv1, wq2, wk2, wv2,
      bq1, bk1, bv1, bq2, bk2, bv2, Wp, Wqkv, Bias);

  proj_mfma_kernel<<<dim3(2 * BB, NN / 64), 256, 0, stream>>>(
      Xp, Wqkv, Bias, Qp1, Kp1, Vp1, Qp2, Kp2, Vp2);

  conv_mfma_kernel<<<dim3(2, 2 * BB, NN / 128), 256, 0, stream>>>(
      Xp, Wp, bd1, bd3, R1, R2);

  attn_kernel<<<dim3(2, BB, NN / 64), 256, 0, stream>>>(
      Qp1, Kp1, Qp2, Kp2, Vp1, Vp2, R1, R2, x1, x2, g1, g2, out);
}

// Round 6
// 301.510 us; speedup vs baseline: 11.2172x; 1.0509x over previous
//
#include <hip/hip_runtime.h>
#include <hip/hip_bf16.h>

// Problem constants
#define CC 256      // channels
#define CKD 32      // q/k projection dim
#define NN 4096     // H*W
#define HH 64
#define WW 64
#define BB 4

#define LOG2E 1.44269504088896f
#define EXPSHIFT 23.0831203874f   // 16 * LOG2E

typedef __attribute__((ext_vector_type(8))) short short8;   // 8 bf16 (4 VGPRs)
typedef __attribute__((ext_vector_type(4))) float floatx4;  // MFMA C/D frag

__device__ __forceinline__ unsigned f2bf(float f) {
  union { float f; unsigned u; } v; v.f = f;
  unsigned r = v.u + 0x7fffu + ((v.u >> 16) & 1u);   // RNE
  return r >> 16;
}
__device__ __forceinline__ unsigned f2bf_fast(float f) {
  return (__float_as_uint(f) + 0x8000u) >> 16;  // round, cheap
}
__device__ __forceinline__ float fast_exp2(float x) {
#if __has_builtin(__builtin_amdgcn_exp2f)
  return __builtin_amdgcn_exp2f(x);
#else
  return __expf(x * 0.693147181f);
#endif
}
__device__ __forceinline__ float bf_lo(unsigned u) { return __uint_as_float(u << 16); }
__device__ __forceinline__ float bf_hi(unsigned u) { return __uint_as_float(u & 0xffff0000u); }

// ---------------------------------------------------------------------------
// Kernel 0a: pack x (fp32 [img][c][n]) -> Xp (bf16 [img][n][c], c contiguous)
// ---------------------------------------------------------------------------
__global__ __launch_bounds__(256) void xpack_kernel(
    const float* __restrict__ x1, const float* __restrict__ x2,
    unsigned short* __restrict__ Xp) {
  const int t = threadIdx.x;
  const int nb = blockIdx.x, cbk = blockIdx.y, img = blockIdx.z;
  const float* X = ((img >> 2) ? x2 : x1) + (size_t)(img & 3) * CC * NN;
  const int n0 = nb * 64, c0 = cbk * 64;
  __shared__ float tile[64][65];
  const int nl = t & 63, cl0 = t >> 6;
#pragma unroll
  for (int i = 0; i < 16; ++i)
    tile[cl0 + i * 4][nl] = X[(size_t)(c0 + cl0 + i * 4) * NN + n0 + nl];
  __syncthreads();
#pragma unroll
  for (int it = 0; it < 2; ++it) {
    int id = it * 256 + t;
    int nl2 = id >> 3, cc = id & 7;
    short8 v;
#pragma unroll
    for (int j = 0; j < 8; ++j) v[j] = (short)f2bf(tile[cc * 8 + j][nl2]);
    *(short8*)(Xp + (size_t)img * NN * CC + (size_t)(n0 + nl2) * CC + c0 + cc * 8) = v;
  }
}

// ---------------------------------------------------------------------------
// Kernel 0b: pack conv weights Wp[tap][o][c] (tap 9 = 1x1), QKV weights
// Wqkv[inp][o=320][c] (q rows scaled by log2e), Bias[inp][320] (fp32).
// ---------------------------------------------------------------------------
__global__ __launch_bounds__(256) void wpack_kernel(
    const float* __restrict__ wd1, const float* __restrict__ wd3,
    const float* __restrict__ wq1, const float* __restrict__ wk1,
    const float* __restrict__ wv1,
    const float* __restrict__ wq2, const float* __restrict__ wk2,
    const float* __restrict__ wv2,
    const float* __restrict__ bq1, const float* __restrict__ bk1,
    const float* __restrict__ bv1,
    const float* __restrict__ bq2, const float* __restrict__ bk2,
    const float* __restrict__ bv2,
    unsigned short* __restrict__ Wp, unsigned short* __restrict__ Wqkv,
    float* __restrict__ Bias) {
  const int id = blockIdx.x * 256 + threadIdx.x;  // 0..65535
#pragma unroll
  for (int tap = 0; tap < 10; ++tap) {
    float v = (tap < 9) ? wd3[(size_t)id * 9 + tap] : wd1[id];
    Wp[(size_t)tap * (CC * CC) + id] = (unsigned short)f2bf(v);
  }
#pragma unroll
  for (int j = 0; j < 3; ++j) {
    int e = id + j * 65536;
    if (e < 2 * 320 * 256) {
      int inp = e / (320 * 256), rem = e % (320 * 256);
      int o = rem >> 8, c = rem & 255;
      float v;
      if (inp == 0)
        v = (o < 32) ? wq1[o * 256 + c] * LOG2E
            : (o < 64) ? wk1[(o - 32) * 256 + c] : wv1[(o - 64) * 256 + c];
      else
        v = (o < 32) ? wq2[o * 256 + c] * LOG2E
            : (o < 64) ? wk2[(o - 32) * 256 + c] : wv2[(o - 64) * 256 + c];
      Wqkv[e] = (unsigned short)f2bf(v);
    }
  }
  if (id < 640) {
    int inp = id / 320, o = id % 320;
    float v;
    if (inp == 0) v = (o < 32) ? bq1[o] * LOG2E
                      : (o < 64) ? bk1[o - 32] : bv1[o - 64];
    else          v = (o < 32) ? bq2[o] * LOG2E
                      : (o < 64) ? bk2[o - 32] : bv2[o - 64];
    Bias[id] = v;
  }
}

// ---------------------------------------------------------------------------
// Kernel 1: MFMA projections. GEMM: [64 pix] x [320 o] x [K=256 c] per block.
// ---------------------------------------------------------------------------
__global__ __launch_bounds__(256) void proj_mfma_kernel(
    const unsigned short* __restrict__ Xp, const unsigned short* __restrict__ Wqkv,
    const float* __restrict__ Bias,
    unsigned short* __restrict__ Qp1, unsigned short* __restrict__ Kp1,
    unsigned short* __restrict__ Vp1,
    unsigned short* __restrict__ Qp2, unsigned short* __restrict__ Kp2,
    unsigned short* __restrict__ Vp2) {
  const int t = threadIdx.x;
  const int w = t >> 6, lane = t & 63;
  const int l15 = lane & 15, g = lane >> 4;
  const int img = blockIdx.x, pb = blockIdx.y;
  const int pix0 = pb * 64;
  const int inp = img >> 2, b = img & 3;
  const unsigned short* Xi = Xp + (size_t)img * NN * CC;
  const unsigned short* Wb = Wqkv + (size_t)inp * 320 * CC;
  const float* Bi = Bias + inp * 320;
  unsigned short* Qp = (inp ? Qp2 : Qp1) + (size_t)b * NN * CKD;
  unsigned short* Kp = (inp ? Kp2 : Kp1) + (size_t)b * NN * CKD;
  unsigned short* Vp = (inp ? Vp2 : Vp1) + (size_t)b * NN * CC;

  __shared__ unsigned short tile[320][72];   // [o][pix]

  floatx4 acc[4][5];
#pragma unroll
  for (int mf = 0; mf < 4; ++mf)
#pragma unroll
    for (int nf = 0; nf < 5; ++nf) acc[mf][nf] = (floatx4){0.f, 0.f, 0.f, 0.f};
  const int o0w = w * 80;

#pragma unroll
  for (int cb = 0; cb < 8; ++cb) {
    short8 a[4], bfr[5];
#pragma unroll
    for (int mf = 0; mf < 4; ++mf)
      a[mf] = *(const short8*)(Xi + (size_t)(pix0 + mf * 16 + l15) * CC + cb * 32 + g * 8);
#pragma unroll
    for (int nf = 0; nf < 5; ++nf)
      bfr[nf] = *(const short8*)(Wb + (size_t)(o0w + nf * 16 + l15) * CC + cb * 32 + g * 8);
#pragma unroll
    for (int nf = 0; nf < 5; ++nf)
#pragma unroll
      for (int mf = 0; mf < 4; ++mf)
        acc[mf][nf] = __builtin_amdgcn_mfma_f32_16x16x32_bf16(
            a[mf], bfr[nf], acc[mf][nf], 0, 0, 0);
  }

#pragma unroll
  for (int nf = 0; nf < 5; ++nf) {
    float bs = Bi[o0w + nf * 16 + l15];
#pragma unroll
    for (int mf = 0; mf < 4; ++mf) {
      uint2 pk;
      pk.x = f2bf(acc[mf][nf][0] + bs) | (f2bf(acc[mf][nf][1] + bs) << 16);
      pk.y = f2bf(acc[mf][nf][2] + bs) | (f2bf(acc[mf][nf][3] + bs) << 16);
      *(uint2*)&tile[o0w + nf * 16 + l15][mf * 16 + g * 4] = pk;
    }
  }
  __syncthreads();

  {
    const int pix = t >> 2, ch = t & 3;
    short8 vq, vk;
#pragma unroll
    for (int e = 0; e < 8; ++e) {
      vq[e] = (short)tile[ch * 8 + e][pix];
      vk[e] = (short)tile[32 + ch * 8 + e][pix];
    }
    *(short8*)(Qp + (size_t)(pix0 + pix) * CKD + ch * 8) = vq;
    *(short8*)(Kp + (size_t)(pix0 + pix) * CKD + ch * 8) = vk;
  }
#pragma unroll
  for (int it = 0; it < 8; ++it) {
    short8 vv = *(const short8*)&tile[64 + t][it * 8];
    *(short8*)(Vp + ((size_t)((pix0 >> 3) + it) * CC + t) * 8) = vv;
  }
}

// ---------------------------------------------------------------------------
// Kernel 2: fused conv + one-pass MFMA flash attention + epilogue.
// grid (2 att, 4 b, 64 rows): id%8 = att+2b -> XCD-pinned V slice.
// Phase A: implicit-GEMM conv for this block's image row (64 pix x 256 o),
//   A = xs pixels (LDS, halo-staged), B = Wp rows (global/L2). D layout
//   matches attn acc (pix on rows, o on l15). Result+bias -> bf16 cres LDS.
// Phase B: software-pipelined j-loop: GEMM1(t+1)+exp+write p_s[nxt] and
//   GEMM2(t) (reads p_s[cur]) in ONE barrier region; K prefetch depth 2,
//   V depth 1. Unrolled x2 for static register buffers.
// Epilogue: out = x + gamma*(acc/l + cres).
// ---------------------------------------------------------------------------
__global__ __launch_bounds__(256, 2) void attn_kernel(
    const unsigned short* __restrict__ Qp1, const unsigned short* __restrict__ Kp1,
    const unsigned short* __restrict__ Qp2, const unsigned short* __restrict__ Kp2,
    const unsigned short* __restrict__ Vp1, const unsigned short* __restrict__ Vp2,
    const unsigned short* __restrict__ Xp, const unsigned short* __restrict__ Wp,
    const float* __restrict__ bd1, const float* __restrict__ bd3,
    const float* __restrict__ x1, const float* __restrict__ x2,
    const float* __restrict__ g1, const float* __restrict__ g2,
    float* __restrict__ out) {
  const int t = threadIdx.x;
  const int w = t >> 6, lane = t & 63;
  const int l15 = lane & 15, g = lane >> 4;
  const int att = blockIdx.x, b = blockIdx.y;
  const int yblk = blockIdx.z;
  const int i0 = yblk * 64;

  const unsigned short *Qp, *Kp, *Vp; const float *x; float gamma; float* o;
  if (att == 0) { Qp = Qp1; Kp = Kp2; Vp = Vp2; x = x1; gamma = g1[0]; o = out; }
  else          { Qp = Qp2; Kp = Kp1; Vp = Vp1; x = x2; gamma = g2[0];
                  o = out + (size_t)BB * CC * NN; }
  Qp += (size_t)b * NN * CKD; Kp += (size_t)b * NN * CKD; Vp += (size_t)b * NN * CC;
  x += (size_t)b * CC * NN; o += (size_t)b * CC * NN;
  const unsigned short* Xi = Xp + (size_t)(att * 4 + b) * NN * CC;  // own image

  __shared__ union {
    unsigned short xs[3][66][72];   // conv pixel tile: rows y-1..y+1, cols -1..64
    unsigned short ps[2][64][72];   // attn P dbuf
  } u;
  __shared__ unsigned short cres[256][68];  // conv result [o][pix] bf16
  __shared__ float l_s[64];

  // Q B-frag (held whole kernel); Q is pre-scaled by log2e
  short8 bq = *(const short8*)(Qp + (size_t)(i0 + w * 16 + l15) * CKD + g * 8);

  floatx4 acc[4][4];
#pragma unroll
  for (int a = 0; a < 4; ++a)
#pragma unroll
    for (int c = 0; c < 4; ++c) acc[a][c] = (floatx4){0.f, 0.f, 0.f, 0.f};
  float l_acc = 0.f;
  const floatx4 zinit = {-EXPSHIFT, -EXPSHIFT, -EXPSHIFT, -EXPSHIFT};

  short8 kr[2][4], vr[2][8];
  auto LOADK = [&](int tt, short8* d) {
    const unsigned short* kb = Kp + ((size_t)tt * 64 + l15) * CKD + g * 8;
#pragma unroll
    for (int js = 0; js < 4; ++js) d[js] = *(const short8*)(kb + js * 16 * CKD);
  };
  auto LOADV = [&](int tt, short8* d) {
#pragma unroll
    for (int ks = 0; ks < 2; ++ks)
#pragma unroll
      for (int cs = 0; cs < 4; ++cs)
        d[ks * 4 + cs] = *(const short8*)(Vp +
            (((size_t)tt * 8 + ks * 4 + g) * CC + (w * 64 + cs * 16 + l15)) * 8);
  };
  auto GEMM1 = [&](const short8* kb, unsigned short (*ps)[72]) {
#pragma unroll
    for (int js = 0; js < 4; ++js) {
      floatx4 s = __builtin_amdgcn_mfma_f32_16x16x32_bf16(kb[js], bq, zinit, 0, 0, 0);
      float p0 = fast_exp2(s[0]);
      float p1 = fast_exp2(s[1]);
      float p2 = fast_exp2(s[2]);
      float p3 = fast_exp2(s[3]);
      l_acc += (p0 + p1) + (p2 + p3);
      unsigned u0 = __float_as_uint(p0) + 0x8000u;
      unsigned u1 = __float_as_uint(p1) + 0x8000u;
      unsigned u2 = __float_as_uint(p2) + 0x8000u;
      unsigned u3 = __float_as_uint(p3) + 0x8000u;
      uint2 pk;
      pk.x = __builtin_amdgcn_perm(u1, u0, 0x07060302u);
      pk.y = __builtin_amdgcn_perm(u3, u2, 0x07060302u);
      *(uint2*)&ps[w * 16 + l15][js * 16 + g * 4] = pk;
    }
  };
  auto GEMM2 = [&](const short8* vb, unsigned short (*ps)[72]) {
#pragma unroll
    for (int ks = 0; ks < 2; ++ks) {
      short8 ap[4];
#pragma unroll
      for (int isub = 0; isub < 4; ++isub)
        ap[isub] = *(const short8*)&ps[isub * 16 + l15][ks * 32 + g * 8];
#pragma unroll
      for (int cs = 0; cs < 4; ++cs)
#pragma unroll
        for (int isub = 0; isub < 4; ++isub)
          acc[isub][cs] = __builtin_amdgcn_mfma_f32_16x16x32_bf16(
              ap[isub], vb[ks * 4 + cs], acc[isub][cs], 0, 0, 0);
    }
  };

  // issue attn prologue loads early (arrive during conv)
  LOADK(0, kr[0]); LOADK(1, kr[1]); LOADV(0, vr[0]);

  // ================= Phase A: conv for this image row =================
  {
    floatx4 ac[4][4];
#pragma unroll
    for (int pm = 0; pm < 4; ++pm)
#pragma unroll
      for (int on = 0; on < 4; ++on) ac[pm][on] = (floatx4){0.f, 0.f, 0.f, 0.f};

    for (int cb = 0; cb < 4; ++cb) {
      const int c0 = cb * 64;
      if (cb) __syncthreads();   // prior tap reads of xs complete
#pragma unroll
      for (int it = 0; it < 7; ++it) {
        int id = it * 256 + t;
        if (id < 1584) {                    // 3*66*8 16B-chunks
          int r = id / 528, rem = id % 528;
          int col = rem >> 3, cc = rem & 7;
          int y = yblk - 1 + r, xx = col - 1;
          short8 v = {0, 0, 0, 0, 0, 0, 0, 0};
          if (y >= 0 && y < HH && xx >= 0 && xx < WW)
            v = *(const short8*)(Xi + (size_t)(y * WW + xx) * CC + c0 + cc * 8);
          *(short8*)&u.xs[r][col][cc * 8] = v;
        }
      }
      __syncthreads();
#pragma unroll
      for (int tap = 0; tap < 10; ++tap) {
        const int dy = (tap < 9) ? tap / 3 - 1 : 0;
        const int dx = (tap < 9) ? tap % 3 - 1 : 0;
        const unsigned short* wrow =
            Wp + ((size_t)tap * CC + w * 64 + l15) * CC + c0 + g * 8;
#pragma unroll
        for (int ks = 0; ks < 2; ++ks) {
          short8 af[4], bw[4];
#pragma unroll
          for (int pm = 0; pm < 4; ++pm)
            af[pm] = *(const short8*)&u.xs[1 + dy][1 + pm * 16 + l15 + dx][ks * 32 + g * 8];
#pragma unroll
          for (int on = 0; on < 4; ++on)
            bw[on] = *(const short8*)(wrow + (size_t)(on * 16) * CC + ks * 32);
#pragma unroll
          for (int pm = 0; pm < 4; ++pm)
#pragma unroll
            for (int on = 0; on < 4; ++on)
              ac[pm][on] = __builtin_amdgcn_mfma_f32_16x16x32_bf16(
                  af[pm], bw[on], ac[pm][on], 0, 0, 0);
        }
      }
    }
    // bias + pack to cres (self-consumed by this wave at epilogue)
#pragma unroll
    for (int on = 0; on < 4; ++on) {
      int oo = w * 64 + on * 16 + l15;
      float bs = bd1[oo] + bd3[oo];
#pragma unroll
      for (int pm = 0; pm < 4; ++pm) {
        uint2 pk;
        pk.x = f2bf_fast(ac[pm][on][0] + bs) | (f2bf_fast(ac[pm][on][1] + bs) << 16);
        pk.y = f2bf_fast(ac[pm][on][2] + bs) | (f2bf_fast(ac[pm][on][3] + bs) << 16);
        *(uint2*)&cres[oo][pm * 16 + g * 4] = pk;
      }
    }
  }
  __syncthreads();   // xs -> ps transition

  // ================= Phase B: pipelined j-loop =================
  GEMM1(kr[0], u.ps[0]);   // tile 0
  __syncthreads();

  for (int jt = 0; jt < 64; jt += 2) {
    // --- sub-iter A: GEMM1(jt+1), GEMM2(jt) ---
    if (jt + 2 < 64) LOADK(jt + 2, kr[0]);
    LOADV(jt + 1, vr[1]);
    GEMM1(kr[1], u.ps[1]);
    GEMM2(vr[0], u.ps[0]);
    __syncthreads();
    // --- sub-iter B: GEMM1(jt+2), GEMM2(jt+1) ---
    if (jt + 3 < 64) LOADK(jt + 3, kr[1]);
    if (jt + 2 < 64) { LOADV(jt + 2, vr[0]); GEMM1(kr[0], u.ps[0]); }
    GEMM2(vr[1], u.ps[1]);
    __syncthreads();
  }

  // l: reduce across g (lane bits 4,5)
  l_acc += __shfl_xor(l_acc, 16);
  l_acc += __shfl_xor(l_acc, 32);
  if (g == 0) l_s[w * 16 + l15] = l_acc;
  __syncthreads();

  // epilogue: out[c][i] = x + gamma*(acc/l + conv)
#pragma unroll
  for (int isub = 0; isub < 4; ++isub) {
    float linv[4];
#pragma unroll
    for (int r = 0; r < 4; ++r) linv[r] = 1.f / l_s[isub * 16 + g * 4 + r];
#pragma unroll
    for (int cs = 0; cs < 4; ++cs) {
      int c = w * 64 + cs * 16 + l15;
      size_t base = (size_t)c * NN + i0 + isub * 16 + g * 4;
      float4 xr = *(const float4*)(x + base);
      uint2 cr = *(const uint2*)&cres[c][isub * 16 + g * 4];
      float4 ov;
      ov.x = xr.x + gamma * (acc[isub][cs][0] * linv[0] + bf_lo(cr.x));
      ov.y = xr.y + gamma * (acc[isub][cs][1] * linv[1] + bf_hi(cr.x));
      ov.z = xr.z + gamma * (acc[isub][cs][2] * linv[2] + bf_lo(cr.y));
      ov.w = xr.w + gamma * (acc[isub][cs][3] * linv[3] + bf_hi(cr.y));
      *(float4*)(o + base) = ov;
    }
  }
}

// ---------------------------------------------------------------------------
extern "C" void kernel_launch(void* const* d_in, const int* in_sizes, int n_in,
                              void* d_out, int out_size, void* d_ws, size_t ws_size,
                              hipStream_t stream) {
  const float* x1  = (const float*)d_in[0];
  const float* x2  = (const float*)d_in[1];
  const float* wq1 = (const float*)d_in[2];
  const float* bq1 = (const float*)d_in[3];
  const float* wk1 = (const float*)d_in[4];
  const float* bk1 = (const float*)d_in[5];
  const float* wv1 = (const float*)d_in[6];
  const float* bv1 = (const float*)d_in[7];
  const float* wq2 = (const float*)d_in[8];
  const float* bq2 = (const float*)d_in[9];
  const float* wk2 = (const float*)d_in[10];
  const float* bk2 = (const float*)d_in[11];
  const float* wv2 = (const float*)d_in[12];
  const float* bv2 = (const float*)d_in[13];
  const float* wd1 = (const float*)d_in[14];
  const float* bd1 = (const float*)d_in[15];
  const float* wd3 = (const float*)d_in[16];
  const float* bd3 = (const float*)d_in[17];
  const float* g1  = (const float*)d_in[18];
  const float* g2  = (const float*)d_in[19];
  float* out = (float*)d_out;

  // workspace layout (bytes)
  const size_t QB = (size_t)BB * NN * CKD * 2;     // 1 MB each
  const size_t VB = (size_t)BB * NN * CC * 2;      // 8 MB each
  const size_t XB = (size_t)2 * BB * NN * CC * 2;  // 16 MB
  const size_t WPB = (size_t)10 * CC * CC * 2;     // 1.31 MB
  const size_t WQB = (size_t)2 * 320 * CC * 2;     // 320 KB
  char* base = (char*)d_ws;
  unsigned short* Qp1 = (unsigned short*)(base);
  unsigned short* Kp1 = (unsigned short*)(base + QB);
  unsigned short* Qp2 = (unsigned short*)(base + 2 * QB);
  unsigned short* Kp2 = (unsigned short*)(base + 3 * QB);
  unsigned short* Vp1 = (unsigned short*)(base + 4 * QB);
  unsigned short* Vp2 = (unsigned short*)(base + 4 * QB + VB);
  unsigned short* Xp  = (unsigned short*)(base + 4 * QB + 2 * VB);
  unsigned short* Wp  = (unsigned short*)(base + 4 * QB + 2 * VB + XB);
  unsigned short* Wqkv = (unsigned short*)(base + 4 * QB + 2 * VB + XB + WPB);
  float* Bias = (float*)(base + 4 * QB + 2 * VB + XB + WPB + WQB);

  xpack_kernel<<<dim3(NN / 64, CC / 64, 2 * BB), 256, 0, stream>>>(x1, x2, Xp);
  wpack_kernel<<<dim3(CC * CC / 256), 256, 0, stream>>>(
      wd1, wd3, wq1, wk1, wv1, wq2, wk2, wv2,
      bq1, bk1, bv1, bq2, bk2, bv2, Wp, Wqkv, Bias);

  proj_mfma_kernel<<<dim3(2 * BB, NN / 64), 256, 0, stream>>>(
      Xp, Wqkv, Bias, Qp1, Kp1, Vp1, Qp2, Kp2, Vp2);

  attn_kernel<<<dim3(2, BB, NN / 64), 256, 0, stream>>>(
      Qp1, Kp1, Qp2, Kp2, Vp1, Vp2, Xp, Wp, bd1, bd3, x1, x2, g1, g2, out);
}